// Round 8
// baseline (413.315 us; speedup 1.0000x reference)
//
#include <hip/hip_runtime.h>

#define N_NODES 100000
#define NPAD    100032   // 1563 * 64, row-tile padded
#define N_EDGES 1600000
#define DIM_IN  128
#define DIM_H   256
#define DIM_C   40

#define NB   391     // buckets of 256 nodes
#define NBLK 391     // edge chunks of 4096
#define CHUNK 4096
#define ECAP 6144    // LDS edge-cache capacity in k_build (ints)

#define CVT_BLOCKS 25000   // N_NODES*64/256
#define WCVT_BLOCKS 1280   // 5 * 256

typedef unsigned short bf16_t;
typedef __attribute__((ext_vector_type(8))) short short8;
typedef __attribute__((ext_vector_type(4))) float f32x4;

__device__ __forceinline__ bf16_t f2b(float f) {
    unsigned int u = __float_as_uint(f);
    unsigned int r = (u + 0x7fffu + ((u >> 16) & 1u)) >> 16;
    return (bf16_t)r;
}

__device__ __forceinline__ void gl_lds16(const void* gsrc, void* ldst) {
    __builtin_amdgcn_global_load_lds(
        (const __attribute__((address_space(1))) void*)gsrc,
        (__attribute__((address_space(3))) void*)ldst,
        16, 0, 0);
}

// ---------------- fused prep: bhist + x->i8 cvt + weight cvt ----------------
// Weights stored in MFMA fragment-staging order: [kstep][chunk][8 bf16],
// chunk = tt*64 + quad*16 + l15 (tt = 16-row tile of B^T). Staging is a
// LINEAR gl_lds16 copy; fragment read Bs[(tt*64+lane)*8] is conflict-free.

__global__ __launch_bounds__(256) void k_prep(
    const int* __restrict__ dst, int* __restrict__ cnt2,
    const float* __restrict__ x, signed char* __restrict__ x8, float* __restrict__ xs,
    const float* __restrict__ w1a, const float* __restrict__ w1b,
    const float* __restrict__ w2a, const float* __restrict__ w2b,
    const float* __restrict__ fcw,
    bf16_t* __restrict__ o1a, bf16_t* __restrict__ o1b,
    bf16_t* __restrict__ o2a, bf16_t* __restrict__ o2b, bf16_t* __restrict__ ofc,
    int* __restrict__ ticket)
{
    __shared__ int h[NB];
    int blk = blockIdx.x, t = threadIdx.x;

    if (blk < NBLK) {
        if (blk == 0 && t == 0) *ticket = 0;
        for (int i = t; i < NB; i += 256) h[i] = 0;
        __syncthreads();
        int base = blk * CHUNK;
        int end = min(base + CHUNK, N_EDGES);
        for (int i = base + t; i < end; i += 256)
            atomicAdd(&h[dst[i] >> 8], 1);
        __syncthreads();
        for (int i = t; i < NB; i += 256) cnt2[blk * NB + i] = h[i];
        return;
    }
    blk -= NBLK;

    if (blk < CVT_BLOCKS) {
        int gid = blk * 256 + t;
        int u = gid >> 6, lane = gid & 63;
        float2 v = *(const float2*)(x + (size_t)u * 128 + lane * 2);
        float m = fmaxf(fabsf(v.x), fabsf(v.y));
        #pragma unroll
        for (int d = 1; d < 64; d <<= 1)
            m = fmaxf(m, __shfl_xor(m, d, 64));
        float inv = (m > 0.f) ? 127.f / m : 0.f;
        int q0 = (int)rintf(v.x * inv);
        int q1 = (int)rintf(v.y * inv);
        unsigned short pk = (unsigned short)((q0 & 0xff) | ((q1 & 0xff) << 8));
        *(unsigned short*)(x8 + ((unsigned)u << 7) + lane * 2) = pk;
        if (lane == 0) xs[u] = (m > 0.f) ? m * (1.f / 127.f) : 0.f;
        return;
    }
    blk -= CVT_BLOCKS;

    // weight cvt into staging order. r = blk>>8, 256 blocks per matrix.
    int r = blk >> 8;
    int idx = (blk & 255) * 256 + t;
    const float* in; bf16_t* out; int K, N, Npad;
    switch (r) {
        case 0: in = w1a; out = o1a; K = 128; N = 256; Npad = 256; break;
        case 1: in = w1b; out = o1b; K = 256; N = 256; Npad = 256; break;
        case 2: in = w2a; out = o2a; K = 256; N = 256; Npad = 256; break;
        case 3: in = w2b; out = o2b; K = 256; N = 256; Npad = 256; break;
        default: in = fcw; out = ofc; K = 256; N = 40;  Npad = 64;  break;
    }
    if (idx >= Npad * K) return;
    int n = idx / K, k = idx - n * K;
    float v = (n < N) ? in[(size_t)k * N + n] : 0.f;
    int kstep = k >> 5, quad = (k >> 3) & 3, e = k & 7;
    int tt = n >> 4, l15 = n & 15;
    size_t opos = (size_t)kstep * (Npad * 32) + ((size_t)(tt * 64 + quad * 16 + l15)) * 8 + e;
    out[opos] = f2b(v);
}

// ---------------- CSR build ----------------

__global__ void k_bscanA(const int* __restrict__ cnt2, int* __restrict__ basep,
                         int* __restrict__ btot, int* __restrict__ ticket,
                         int* __restrict__ boff) {
    __shared__ int s[512];
    __shared__ int isLast;
    int t = threadIdx.x, b = blockIdx.x;
    int v = (t < NBLK) ? cnt2[t * NB + b] : 0;
    s[t] = v;
    __syncthreads();
    #pragma unroll
    for (int d = 1; d < 512; d <<= 1) {
        int tv = (t >= d) ? s[t - d] : 0;
        __syncthreads();
        s[t] += tv;
        __syncthreads();
    }
    if (t < NBLK) basep[t * NB + b] = s[t] - v;
    if (t == 511) atomicExch(&btot[b], s[511]);
    __syncthreads();
    if (t == 0) {
        __threadfence();
        int old = atomicAdd(ticket, 1);
        isLast = (old == NB - 1);
    }
    __syncthreads();
    if (!isLast) return;

    __threadfence();
    int v2 = (t < NB) ? atomicAdd(&btot[t], 0) : 0;
    s[t] = v2;
    __syncthreads();
    #pragma unroll
    for (int d = 1; d < 512; d <<= 1) {
        int tv = (t >= d) ? s[t - d] : 0;
        __syncthreads();
        s[t] += tv;
        __syncthreads();
    }
    if (t < NB) boff[t] = s[t] - v2;
    if (t == NB - 1) boff[NB] = s[t];
}

__global__ void k_bscatter(const int* __restrict__ src, const int* __restrict__ dst,
                           const int* __restrict__ basep, const int* __restrict__ boff,
                           int* __restrict__ ebuf, int e) {
    __shared__ int cur[NB];
    int t = threadIdx.x, blk = blockIdx.x;
    for (int i = t; i < NB; i += 256) cur[i] = basep[blk * NB + i] + boff[i];
    __syncthreads();
    int base = blk * CHUNK;
    int end = min(base + CHUNK, e);
    for (int i = base + t; i < end; i += 256) {
        int sv = src[i], dv = dst[i];
        int pos = atomicAdd(&cur[dv >> 8], 1);
        ebuf[pos] = sv | ((dv & 255) << 24);
    }
}

__global__ __launch_bounds__(256) void k_build(const int* __restrict__ ebuf,
                                               const int* __restrict__ boff,
                                               int* __restrict__ off,
                                               int* __restrict__ csr) {
    __shared__ int ec[ECAP];
    __shared__ int h[256];
    __shared__ int cur[256];
    int t = threadIdx.x, b = blockIdx.x;
    int node0 = b << 8;
    int e0 = boff[b], e1 = boff[b + 1];
    int ne = e1 - e0;
    bool fits = (ne <= ECAP);
    h[t] = 0;
    __syncthreads();
    if (fits) {
        for (int i = t; i < ne; i += 256) {
            int p = ebuf[e0 + i];
            ec[i] = p;
            atomicAdd(&h[(unsigned)p >> 24], 1);
        }
    } else {
        for (int i = t; i < ne; i += 256)
            atomicAdd(&h[(unsigned)ebuf[e0 + i] >> 24], 1);
    }
    __syncthreads();
    int mydeg = h[t];
    #pragma unroll
    for (int d = 1; d < 256; d <<= 1) {
        int tv = (t >= d) ? h[t - d] : 0;
        __syncthreads();
        h[t] += tv;
        __syncthreads();
    }
    int node = node0 + t;
    if (node < N_NODES) off[node + 1] = e0 + h[t];
    if (b == 0 && t == 0) off[0] = 0;
    cur[t] = e0 + h[t] - mydeg;
    __syncthreads();
    if (fits) {
        for (int i = t; i < ne; i += 256) {
            int p = ec[i];
            int pos = atomicAdd(&cur[(unsigned)p >> 24], 1);
            csr[pos] = p & 0xFFFFFF;
        }
    } else {
        for (int i = t; i < ne; i += 256) {
            int p = ebuf[e0 + i];
            int pos = atomicAdd(&cur[(unsigned)p >> 24], 1);
            csr[pos] = p & 0xFFFFFF;
        }
    }
}

// ---------------- layer-1 aggregation (i8 gather) ----------------
// Gather loop untouched (frozen, miss-path floor). Epilogue writes rst in
// A-fragment-staging order.

__global__ void k_agg_i8(const signed char* __restrict__ h8, const float* __restrict__ hs,
                         const int* __restrict__ off, const int* __restrict__ csr,
                         const float* __restrict__ eps_p,
                         bf16_t* __restrict__ rst, int n) {
    int gid = blockIdx.x * blockDim.x + threadIdx.x;
    int u = __builtin_amdgcn_readfirstlane(gid >> 6);   // wave-uniform
    int lane = threadIdx.x & 63;
    if (u >= n) return;

    float acc0 = 0.f, acc1 = 0.f;
    int r0 = off[u], r1 = off[u + 1];
    unsigned loff = lane * 2u;

    for (int base = r0; base < r1; base += 64) {
        int m = r1 - base; if (m > 64) m = 64;           // uniform
        int li = (lane < m) ? lane : (m - 1);
        int iv = csr[base + li];                         // one coalesced load
        for (int c = 0; c < m; c += 16) {
            int s[16]; float sc[16]; unsigned v[16];
            #pragma unroll
            for (int t = 0; t < 16; t++)
                s[t] = __builtin_amdgcn_readlane(iv, c + t);   // SGPR indices
            #pragma unroll
            for (int t = 0; t < 16; t++)
                sc[t] = (c + t < m) ? hs[s[t]] : 0.f;          // scalar loads
            #pragma unroll
            for (int t = 0; t < 16; t++)
                v[t] = *(const unsigned short*)(h8 + (((unsigned)s[t] << 7) + loff));
            #pragma unroll
            for (int t = 0; t < 16; t++) {
                acc0 += (float)(int)(signed char)(v[t] & 0xffu) * sc[t];
                acc1 += (float)(int)(signed char)(v[t] >> 8) * sc[t];
            }
        }
    }

    float scu = hs[u] * (1.0f + eps_p[0]);
    unsigned vu = *(const unsigned short*)(h8 + (((unsigned)u << 7) + loff));
    float o0 = (float)(int)(signed char)(vu & 0xffu) * scu + acc0;
    float o1 = (float)(int)(signed char)(vu >> 8) * scu + acc1;

    int R = u >> 6, rr = u & 63;
    int i4 = rr >> 4, l15v = rr & 15;
    int ks = lane >> 4, quad = (lane >> 2) & 3, e2 = (lane & 3) * 2;
    size_t pos = (((size_t)R * 4 + ks) * 256 + (size_t)(i4 * 64 + quad * 16 + l15v)) * 8 + e2;
    *(unsigned int*)(rst + pos) =
        (unsigned int)f2b(o0) | ((unsigned int)f2b(o1) << 16);
}

// ---------------- layer-2 aggregation (u8 gather) ----------------

__global__ void k_agg_u8(const unsigned char* __restrict__ h8,
                         const float* __restrict__ hs,
                         const int* __restrict__ off, const int* __restrict__ csr,
                         const float* __restrict__ eps_p,
                         bf16_t* __restrict__ rst, int n) {
    int gid = blockIdx.x * blockDim.x + threadIdx.x;
    int u = __builtin_amdgcn_readfirstlane(gid >> 6);   // wave-uniform
    int lane = threadIdx.x & 63;
    if (u >= n) return;

    float acc[4] = {0.f, 0.f, 0.f, 0.f};
    int r0 = off[u], r1 = off[u + 1];
    unsigned loff = lane * 4u;

    for (int base = r0; base < r1; base += 64) {
        int m = r1 - base; if (m > 64) m = 64;           // uniform
        int li = (lane < m) ? lane : (m - 1);
        int iv = csr[base + li];                         // one coalesced load
        for (int c = 0; c < m; c += 16) {
            int s[16]; float sc[16]; unsigned int v[16];
            #pragma unroll
            for (int t = 0; t < 16; t++)
                s[t] = __builtin_amdgcn_readlane(iv, c + t);   // SGPR indices
            #pragma unroll
            for (int t = 0; t < 16; t++)
                sc[t] = (c + t < m) ? hs[s[t]] : 0.f;          // scalar loads
            #pragma unroll
            for (int t = 0; t < 16; t++)
                v[t] = *(const unsigned int*)(h8 + (((unsigned)s[t] << 8) + loff));
            #pragma unroll
            for (int t = 0; t < 16; t++) {
                acc[0] += (float)(v[t] & 0xffu) * sc[t];
                acc[1] += (float)((v[t] >> 8) & 0xffu) * sc[t];
                acc[2] += (float)((v[t] >> 16) & 0xffu) * sc[t];
                acc[3] += (float)(v[t] >> 24) * sc[t];
            }
        }
    }

    float ep = 1.0f + eps_p[0];
    unsigned int vu = *(const unsigned int*)(h8 + (((unsigned)u << 8) + loff));
    float scu = hs[u] * ep;
    float o0 = (float)(vu & 0xffu) * scu + acc[0];
    float o1 = (float)((vu >> 8) & 0xffu) * scu + acc[1];
    float o2 = (float)((vu >> 16) & 0xffu) * scu + acc[2];
    float o3 = (float)(vu >> 24) * scu + acc[3];
    uint2 ov;
    ov.x = (unsigned int)f2b(o0) | ((unsigned int)f2b(o1) << 16);
    ov.y = (unsigned int)f2b(o2) | ((unsigned int)f2b(o3) << 16);

    int R = u >> 6, rr = u & 63;
    int i4 = rr >> 4, l15v = rr & 15;
    int ks = lane >> 3, quad = (lane >> 1) & 3, e4 = (lane & 1) * 4;
    size_t pos = (((size_t)R * 8 + ks) * 256 + (size_t)(i4 * 64 + quad * 16 + l15v)) * 8 + e4;
    *(uint2*)(rst + pos) = ov;
}

// ---------------- fused 2-GEMM MLP, 64-row tile, 8 waves (512 thr) ----------------
// A, B, AND Ts all in fragment-staging order -> every LDS read is linear in
// lane (conflict-free); gl_lds16 staging is linear. 8 waves each own a 32-col
// slice (wn=wave*32): 4 waves/SIMD of TLP at 2 blocks/CU. Double-buffered
// As/Bs, counted vmcnt (waves0-3: 3, waves4-7: 2; ph2: 2; fc: 1) keeps
// prefetch in flight across barriers.
// OUT8: u8 + per-row scale. FUSE_FC: phase 3 = h @ fc + bias -> fp32 out.

template <int K1, bool OUT8, bool FUSE_FC>
__global__ __launch_bounds__(512, 4) void k_mlp(
    const bf16_t* __restrict__ A, const bf16_t* __restrict__ W1t,
    const bf16_t* __restrict__ W2t, bf16_t* __restrict__ H,
    unsigned char* __restrict__ H8, float* __restrict__ Hs,
    const bf16_t* __restrict__ FCt, const float* __restrict__ fc_b,
    float* __restrict__ Cout, int M)
{
    constexpr int NS1 = K1 / 32;
    __shared__ __align__(16) bf16_t As[2][64 * 32];     // 8 KB
    __shared__ __align__(16) bf16_t Bs[2][256 * 32];    // 32 KB
    __shared__ __align__(16) bf16_t Ts[64 * 256];       // 32 KB, staged layout
    __shared__ int rmax[64];

    int tid = threadIdx.x;
    int wave = tid >> 6, lane = tid & 63;
    int l15 = lane & 15, quad = lane >> 4;
    int bm = blockIdx.x * 64;
    int wn = wave * 32;

    auto stageA = [&](int kstep, int b) {
        if (tid < 256)
            gl_lds16(A + ((size_t)blockIdx.x * NS1 + kstep) * 2048 + tid * 8, &As[b][tid * 8]);
    };
    auto stageB = [&](const bf16_t* W, int kstep, int b) {
        #pragma unroll
        for (int l = 0; l < 2; l++) {
            int c = l * 512 + tid;
            gl_lds16(W + ((size_t)kstep * 1024 + c) * 8, &Bs[b][c * 8]);
        }
    };

    // staged Ts element index for (row, col) in [64]x[256]
    auto ts_el = [&](int row, int col) {
        return ((col >> 5) * 4 + (row >> 4)) * 512 +
               ((((col >> 3) & 3) * 16) + (row & 15)) * 8 + (col & 7);
    };

    f32x4 acc[4][2];
    #pragma unroll
    for (int i = 0; i < 4; i++)
        #pragma unroll
        for (int j = 0; j < 2; j++) acc[i][j] = 0.f;

    // ---- phase 1: A (LDS) x W1t (LDS) ----
    stageA(0, 0); stageB(W1t, 0, 0);
    #pragma unroll
    for (int k = 0; k < NS1; k++) {
        int cur = k & 1;
        if (k + 1 < NS1) {
            stageA(k + 1, cur ^ 1); stageB(W1t, k + 1, cur ^ 1);
            if (tid < 256) { asm volatile("s_waitcnt vmcnt(3)" ::: "memory"); }
            else           { asm volatile("s_waitcnt vmcnt(2)" ::: "memory"); }
        } else {
            asm volatile("s_waitcnt vmcnt(0)" ::: "memory");
        }
        __builtin_amdgcn_sched_barrier(0);
        __builtin_amdgcn_s_barrier();

        short8 af[4], bfv[2];
        #pragma unroll
        for (int i = 0; i < 4; i++)
            af[i] = *(const short8*)&As[cur][(i * 64 + lane) * 8];
        #pragma unroll
        for (int j = 0; j < 2; j++)
            bfv[j] = *(const short8*)&Bs[cur][((wave * 2 + j) * 64 + lane) * 8];

        #pragma unroll
        for (int i = 0; i < 4; i++)
            #pragma unroll
            for (int j = 0; j < 2; j++)
                acc[i][j] = __builtin_amdgcn_mfma_f32_16x16x32_bf16(af[i], bfv[j], acc[i][j], 0, 0, 0);

        asm volatile("s_waitcnt lgkmcnt(0)" ::: "memory");
        __builtin_amdgcn_sched_barrier(0);
        __builtin_amdgcn_s_barrier();
    }

    // write relu(h1) into staged Ts
    #pragma unroll
    for (int i = 0; i < 4; i++)
        #pragma unroll
        for (int j = 0; j < 2; j++) {
            int col = wn + j * 16 + l15;
            #pragma unroll
            for (int r = 0; r < 4; r++) {
                int row = i * 16 + quad * 4 + r;
                Ts[ts_el(row, col)] = f2b(fmaxf(acc[i][j][r], 0.f));
            }
        }

    #pragma unroll
    for (int i = 0; i < 4; i++)
        #pragma unroll
        for (int j = 0; j < 2; j++) acc[i][j] = 0.f;
    __syncthreads();

    // ---- phase 2: relu(T) (LDS, staged) x W2t (LDS) ----
    stageB(W2t, 0, 0);
    #pragma unroll
    for (int k = 0; k < 8; k++) {
        int cur = k & 1;
        if (k + 1 < 8) {
            stageB(W2t, k + 1, cur ^ 1);
            asm volatile("s_waitcnt vmcnt(2)" ::: "memory");
        } else {
            asm volatile("s_waitcnt vmcnt(0)" ::: "memory");
        }
        __builtin_amdgcn_sched_barrier(0);
        __builtin_amdgcn_s_barrier();

        short8 af[4], bfv[2];
        #pragma unroll
        for (int i = 0; i < 4; i++)
            af[i] = *(const short8*)&Ts[((k * 4 + i) * 64 + lane) * 8];
        #pragma unroll
        for (int j = 0; j < 2; j++)
            bfv[j] = *(const short8*)&Bs[cur][((wave * 2 + j) * 64 + lane) * 8];

        #pragma unroll
        for (int i = 0; i < 4; i++)
            #pragma unroll
            for (int j = 0; j < 2; j++)
                acc[i][j] = __builtin_amdgcn_mfma_f32_16x16x32_bf16(af[i], bfv[j], acc[i][j], 0, 0, 0);

        asm volatile("s_waitcnt lgkmcnt(0)" ::: "memory");
        __builtin_amdgcn_sched_barrier(0);
        __builtin_amdgcn_s_barrier();
    }

    if constexpr (OUT8) {
        if (tid < 64) rmax[tid] = 0;
        __syncthreads();
        #pragma unroll
        for (int i = 0; i < 4; i++)
            #pragma unroll
            for (int r = 0; r < 4; r++) {
                float m = 0.f;
                #pragma unroll
                for (int j = 0; j < 2; j++) m = fmaxf(m, acc[i][j][r]);
                atomicMax(&rmax[i * 16 + quad * 4 + r], __float_as_int(m));
            }
        __syncthreads();
        #pragma unroll
        for (int i = 0; i < 4; i++) {
            #pragma unroll
            for (int r = 0; r < 4; r++) {
                int row = i * 16 + quad * 4 + r;
                int rowg = bm + row;
                if (rowg >= M) continue;
                float rm = __int_as_float(rmax[row]);
                float inv = (rm > 0.f) ? 255.f / rm : 0.f;
                #pragma unroll
                for (int j = 0; j < 2; j++) {
                    int col = wn + j * 16 + l15;
                    float v = fmaxf(acc[i][j][r], 0.f);
                    unsigned q = (unsigned)(v * inv + 0.5f);
                    if (q > 255u) q = 255u;
                    H8[(size_t)rowg * 256 + col] = (unsigned char)q;
                }
                if (wave == 0 && l15 == 0)
                    Hs[rowg] = rm * (1.f / 255.f);
            }
        }
    } else if constexpr (FUSE_FC) {
        // write relu'd h tile back into staged Ts, then phase 3: out = h@fc + b
        #pragma unroll
        for (int i = 0; i < 4; i++)
            #pragma unroll
            for (int j = 0; j < 2; j++) {
                int col = wn + j * 16 + l15;
                #pragma unroll
                for (int r = 0; r < 4; r++) {
                    int row = i * 16 + quad * 4 + r;
                    Ts[ts_el(row, col)] = f2b(fmaxf(acc[i][j][r], 0.f));
                }
            }
        __syncthreads();

        f32x4 acc3[3];
        #pragma unroll
        for (int j = 0; j < 3; j++) acc3[j] = 0.f;

        // staging-order FCt: 256 chunks per kstep (64 N-rows)
        auto stage3 = [&](int kstep, int b) {
            if (tid < 256)
                gl_lds16(FCt + ((size_t)kstep * 256 + tid) * 8, &Bs[b][tid * 8]);
        };

        // waves 0-3 compute rows [wave*16, wave*16+16), cols 0..47 (40 real)
        stage3(0, 0);
        #pragma unroll
        for (int k = 0; k < 8; k++) {
            int cur = k & 1;
            if (k + 1 < 8) {
                stage3(k + 1, cur ^ 1);
                if (tid < 256) { asm volatile("s_waitcnt vmcnt(1)" ::: "memory"); }
            } else {
                if (tid < 256) { asm volatile("s_waitcnt vmcnt(0)" ::: "memory"); }
            }
            __builtin_amdgcn_sched_barrier(0);
            __builtin_amdgcn_s_barrier();

            if (tid < 256) {
                short8 af = *(const short8*)&Ts[((k * 4 + wave) * 64 + lane) * 8];
                #pragma unroll
                for (int j = 0; j < 3; j++) {
                    short8 bfv = *(const short8*)&Bs[cur][((j * 64) + lane) * 8];
                    acc3[j] = __builtin_amdgcn_mfma_f32_16x16x32_bf16(af, bfv, acc3[j], 0, 0, 0);
                }
                asm volatile("s_waitcnt lgkmcnt(0)" ::: "memory");
            }
            __builtin_amdgcn_sched_barrier(0);
            __builtin_amdgcn_s_barrier();
        }

        if (tid < 256) {
            #pragma unroll
            for (int j = 0; j < 3; j++) {
                int col = j * 16 + l15;
                if (col >= DIM_C) continue;
                float bv = fc_b[col];
                #pragma unroll
                for (int r = 0; r < 4; r++) {
                    int rowg = bm + wave * 16 + quad * 4 + r;
                    if (rowg < M)
                        Cout[(size_t)rowg * DIM_C + col] = acc3[j][r] + bv;
                }
            }
        }
    } else {
        #pragma unroll
        for (int j = 0; j < 2; j++) {
            int col = wn + j * 16 + l15;
            #pragma unroll
            for (int i = 0; i < 4; i++) {
                #pragma unroll
                for (int r = 0; r < 4; r++) {
                    int rowg = bm + i * 16 + quad * 4 + r;
                    if (rowg < M)
                        H[(size_t)rowg * 256 + col] = f2b(fmaxf(acc[i][j][r], 0.f));
                }
            }
        }
    }
}

// ---------------- launch ----------------

static inline size_t rnd256(size_t x) { return (x + 255) & ~(size_t)255; }

extern "C" void kernel_launch(void* const* d_in, const int* in_sizes, int n_in,
                              void* d_out, int out_size, void* d_ws, size_t ws_size,
                              hipStream_t stream) {
    const float* x    = (const float*)d_in[0];
    const int*   src  = (const int*)d_in[1];
    const int*   dst  = (const int*)d_in[2];
    const float* eps1 = (const float*)d_in[3];
    const float* w1a  = (const float*)d_in[4];
    const float* w1b  = (const float*)d_in[5];
    const float* eps2 = (const float*)d_in[6];
    const float* w2a  = (const float*)d_in[7];
    const float* w2b  = (const float*)d_in[8];
    const float* fc_w = (const float*)d_in[9];
    const float* fc_b = (const float*)d_in[10];
    float* out = (float*)d_out;

    char* w = (char*)d_ws;
    int* off  = (int*)w; w += rnd256(sizeof(int) * (size_t)(N_NODES + 1));
    int* csr  = (int*)w; w += rnd256(sizeof(int) * (size_t)N_EDGES);
    int* cnt2  = (int*)w; w += rnd256(sizeof(int) * (size_t)NBLK * NB);
    int* basep = (int*)w; w += rnd256(sizeof(int) * (size_t)NBLK * NB);
    int* btot  = (int*)w; w += rnd256(sizeof(int) * 512);
    int* boff  = (int*)w; w += rnd256(sizeof(int) * (NB + 1));
    bf16_t* w1a_t = (bf16_t*)w; w += rnd256(2 * (size_t)DIM_H * DIM_IN);
    bf16_t* w1b_t = (bf16_t*)w; w += rnd256(2 * (size_t)DIM_H * DIM_H);
    bf16_t* w2a_t = (bf16_t*)w; w += rnd256(2 * (size_t)DIM_H * DIM_H);
    bf16_t* w2b_t = (bf16_t*)w; w += rnd256(2 * (size_t)DIM_H * DIM_H);
    bf16_t* fc_t  = (bf16_t*)w; w += rnd256(2 * (size_t)128 * DIM_H);
    signed char* x8 = (signed char*)w; w += rnd256((size_t)N_NODES * DIM_IN);
    float* xs = (float*)w; w += rnd256(sizeof(float) * (size_t)N_NODES);
    unsigned char* h8 = (unsigned char*)w; w += rnd256((size_t)N_NODES * DIM_H);
    float* hs = (float*)w; w += rnd256(sizeof(float) * (size_t)N_NODES);
    bf16_t* R12 = (bf16_t*)w; w += rnd256(2 * (size_t)NPAD * DIM_H);
    bf16_t* R3  = (bf16_t*)w; w += rnd256(2 * (size_t)NPAD * DIM_H);

    bf16_t* rst1 = R12;       // [1563][4][256][8] staging order, 25.6 MB
    int* ebuf = (int*)R3;     // 6.4 MB, dead before layer-2 agg writes R3
    int* ticket = btot + 500; // btot block has 512 ints, NB=391 used

    // ---- prep (hist + cvt + wcvt fused) ----
    k_prep<<<NBLK + CVT_BLOCKS + WCVT_BLOCKS, 256, 0, stream>>>(
        dst, cnt2, x, x8, xs, w1a, w1b, w2a, w2b, fc_w,
        w1a_t, w1b_t, w2a_t, w2b_t, fc_t, ticket);

    // ---- CSR build (scanA + scan2 fused via ticket) ----
    k_bscanA<<<NB, 512, 0, stream>>>(cnt2, basep, btot, ticket, boff);
    k_bscatter<<<NBLK, 256, 0, stream>>>(src, dst, basep, boff, ebuf, N_EDGES);
    k_build<<<NB, 256, 0, stream>>>(ebuf, boff, off, csr);

    const int agg_blocks = (N_NODES * 64 + 255) / 256;
    const int mlp_blocks = NPAD / 64;   // 1563

    // ---- layer 1: i8 agg -> MLP (u8 output + row scales) ----
    k_agg_i8<<<agg_blocks, 256, 0, stream>>>(x8, xs, off, csr, eps1, rst1, N_NODES);
    k_mlp<DIM_IN, true, false><<<mlp_blocks, 512, 0, stream>>>(
        rst1, w1a_t, w1b_t, nullptr, h8, hs, nullptr, nullptr, nullptr, N_NODES);

    // ---- layer 2: u8 agg -> MLP + fused fc (fp32 out) ----
    k_agg_u8<<<agg_blocks, 256, 0, stream>>>(h8, hs, off, csr, eps2, (bf16_t*)R3, N_NODES);
    k_mlp<DIM_H, false, true><<<mlp_blocks, 512, 0, stream>>>(
        (bf16_t*)R3, w2a_t, w2b_t, nullptr, nullptr, nullptr, fc_t, fc_b, out, N_NODES);
}

// Round 9
// 408.792 us; speedup vs baseline: 1.0111x; 1.0111x over previous
//
#include <hip/hip_runtime.h>

#define N_NODES 100000
#define NPAD    100032   // 1563 * 64, row-tile padded
#define N_EDGES 1600000
#define DIM_IN  128
#define DIM_H   256
#define DIM_C   40

#define NB   391     // buckets of 256 nodes
#define NBLK 391     // edge chunks of 4096
#define CHUNK 4096
#define ECAP 6144    // LDS edge-cache capacity in k_build (ints)

#define CVT_BLOCKS 25000   // N_NODES*64/256
#define WCVT_BLOCKS 1280   // 5 * 256

typedef unsigned short bf16_t;
typedef __attribute__((ext_vector_type(8))) short short8;
typedef __attribute__((ext_vector_type(4))) float f32x4;

__device__ __forceinline__ bf16_t f2b(float f) {
    unsigned int u = __float_as_uint(f);
    unsigned int r = (u + 0x7fffu + ((u >> 16) & 1u)) >> 16;
    return (bf16_t)r;
}

__device__ __forceinline__ void gl_lds16(const void* gsrc, void* ldst) {
    __builtin_amdgcn_global_load_lds(
        (const __attribute__((address_space(1))) void*)gsrc,
        (__attribute__((address_space(3))) void*)ldst,
        16, 0, 0);
}

// ---------------- fused prep: bhist + x->i8 cvt + weight cvt ----------------
// Weights stored in MFMA fragment-staging order: [kstep][chunk][8 bf16],
// chunk = tt*64 + quad*16 + l15 (tt = 16-row tile of B^T). Staging is a
// LINEAR gl_lds16 copy; fragment read Bs[(tt*64+lane)*8] is conflict-free.

__global__ __launch_bounds__(256) void k_prep(
    const int* __restrict__ dst, int* __restrict__ cnt2,
    const float* __restrict__ x, signed char* __restrict__ x8, float* __restrict__ xs,
    const float* __restrict__ w1a, const float* __restrict__ w1b,
    const float* __restrict__ w2a, const float* __restrict__ w2b,
    const float* __restrict__ fcw,
    bf16_t* __restrict__ o1a, bf16_t* __restrict__ o1b,
    bf16_t* __restrict__ o2a, bf16_t* __restrict__ o2b, bf16_t* __restrict__ ofc,
    int* __restrict__ ticket)
{
    __shared__ int h[NB];
    int blk = blockIdx.x, t = threadIdx.x;

    if (blk < NBLK) {
        if (blk == 0 && t == 0) *ticket = 0;
        for (int i = t; i < NB; i += 256) h[i] = 0;
        __syncthreads();
        int base = blk * CHUNK;
        int end = min(base + CHUNK, N_EDGES);
        for (int i = base + t; i < end; i += 256)
            atomicAdd(&h[dst[i] >> 8], 1);
        __syncthreads();
        for (int i = t; i < NB; i += 256) cnt2[blk * NB + i] = h[i];
        return;
    }
    blk -= NBLK;

    if (blk < CVT_BLOCKS) {
        int gid = blk * 256 + t;
        int u = gid >> 6, lane = gid & 63;
        float2 v = *(const float2*)(x + (size_t)u * 128 + lane * 2);
        float m = fmaxf(fabsf(v.x), fabsf(v.y));
        #pragma unroll
        for (int d = 1; d < 64; d <<= 1)
            m = fmaxf(m, __shfl_xor(m, d, 64));
        float inv = (m > 0.f) ? 127.f / m : 0.f;
        int q0 = (int)rintf(v.x * inv);
        int q1 = (int)rintf(v.y * inv);
        unsigned short pk = (unsigned short)((q0 & 0xff) | ((q1 & 0xff) << 8));
        *(unsigned short*)(x8 + ((unsigned)u << 7) + lane * 2) = pk;
        if (lane == 0) xs[u] = (m > 0.f) ? m * (1.f / 127.f) : 0.f;
        return;
    }
    blk -= CVT_BLOCKS;

    // weight cvt into staging order. r = blk>>8, 256 blocks per matrix.
    int r = blk >> 8;
    int idx = (blk & 255) * 256 + t;
    const float* in; bf16_t* out; int K, N, Npad;
    switch (r) {
        case 0: in = w1a; out = o1a; K = 128; N = 256; Npad = 256; break;
        case 1: in = w1b; out = o1b; K = 256; N = 256; Npad = 256; break;
        case 2: in = w2a; out = o2a; K = 256; N = 256; Npad = 256; break;
        case 3: in = w2b; out = o2b; K = 256; N = 256; Npad = 256; break;
        default: in = fcw; out = ofc; K = 256; N = 40;  Npad = 64;  break;
    }
    if (idx >= Npad * K) return;
    int n = idx / K, k = idx - n * K;
    float v = (n < N) ? in[(size_t)k * N + n] : 0.f;
    int kstep = k >> 5, quad = (k >> 3) & 3, e = k & 7;
    int tt = n >> 4, l15 = n & 15;
    size_t opos = (size_t)kstep * (Npad * 32) + ((size_t)(tt * 64 + quad * 16 + l15)) * 8 + e;
    out[opos] = f2b(v);
}

// ---------------- CSR build ----------------

__global__ void k_bscanA(const int* __restrict__ cnt2, int* __restrict__ basep,
                         int* __restrict__ btot, int* __restrict__ ticket,
                         int* __restrict__ boff) {
    __shared__ int s[512];
    __shared__ int isLast;
    int t = threadIdx.x, b = blockIdx.x;
    int v = (t < NBLK) ? cnt2[t * NB + b] : 0;
    s[t] = v;
    __syncthreads();
    #pragma unroll
    for (int d = 1; d < 512; d <<= 1) {
        int tv = (t >= d) ? s[t - d] : 0;
        __syncthreads();
        s[t] += tv;
        __syncthreads();
    }
    if (t < NBLK) basep[t * NB + b] = s[t] - v;
    if (t == 511) atomicExch(&btot[b], s[511]);
    __syncthreads();
    if (t == 0) {
        __threadfence();
        int old = atomicAdd(ticket, 1);
        isLast = (old == NB - 1);
    }
    __syncthreads();
    if (!isLast) return;

    __threadfence();
    int v2 = (t < NB) ? atomicAdd(&btot[t], 0) : 0;
    s[t] = v2;
    __syncthreads();
    #pragma unroll
    for (int d = 1; d < 512; d <<= 1) {
        int tv = (t >= d) ? s[t - d] : 0;
        __syncthreads();
        s[t] += tv;
        __syncthreads();
    }
    if (t < NB) boff[t] = s[t] - v2;
    if (t == NB - 1) boff[NB] = s[t];
}

__global__ void k_bscatter(const int* __restrict__ src, const int* __restrict__ dst,
                           const int* __restrict__ basep, const int* __restrict__ boff,
                           int* __restrict__ ebuf, int e) {
    __shared__ int cur[NB];
    int t = threadIdx.x, blk = blockIdx.x;
    for (int i = t; i < NB; i += 256) cur[i] = basep[blk * NB + i] + boff[i];
    __syncthreads();
    int base = blk * CHUNK;
    int end = min(base + CHUNK, e);
    for (int i = base + t; i < end; i += 256) {
        int sv = src[i], dv = dst[i];
        int pos = atomicAdd(&cur[dv >> 8], 1);
        ebuf[pos] = sv | ((dv & 255) << 24);
    }
}

__global__ __launch_bounds__(256) void k_build(const int* __restrict__ ebuf,
                                               const int* __restrict__ boff,
                                               int* __restrict__ off,
                                               int* __restrict__ csr) {
    __shared__ int ec[ECAP];
    __shared__ int h[256];
    __shared__ int cur[256];
    int t = threadIdx.x, b = blockIdx.x;
    int node0 = b << 8;
    int e0 = boff[b], e1 = boff[b + 1];
    int ne = e1 - e0;
    bool fits = (ne <= ECAP);
    h[t] = 0;
    __syncthreads();
    if (fits) {
        for (int i = t; i < ne; i += 256) {
            int p = ebuf[e0 + i];
            ec[i] = p;
            atomicAdd(&h[(unsigned)p >> 24], 1);
        }
    } else {
        for (int i = t; i < ne; i += 256)
            atomicAdd(&h[(unsigned)ebuf[e0 + i] >> 24], 1);
    }
    __syncthreads();
    int mydeg = h[t];
    #pragma unroll
    for (int d = 1; d < 256; d <<= 1) {
        int tv = (t >= d) ? h[t - d] : 0;
        __syncthreads();
        h[t] += tv;
        __syncthreads();
    }
    int node = node0 + t;
    if (node < N_NODES) off[node + 1] = e0 + h[t];
    if (b == 0 && t == 0) off[0] = 0;
    cur[t] = e0 + h[t] - mydeg;
    __syncthreads();
    if (fits) {
        for (int i = t; i < ne; i += 256) {
            int p = ec[i];
            int pos = atomicAdd(&cur[(unsigned)p >> 24], 1);
            csr[pos] = p & 0xFFFFFF;
        }
    } else {
        for (int i = t; i < ne; i += 256) {
            int p = ebuf[e0 + i];
            int pos = atomicAdd(&cur[(unsigned)p >> 24], 1);
            csr[pos] = p & 0xFFFFFF;
        }
    }
}

// ---------------- layer-1 aggregation (i8 gather) ----------------
// Gather loop untouched (frozen, miss-path floor). Epilogue writes rst in
// A-fragment-staging order.

__global__ void k_agg_i8(const signed char* __restrict__ h8, const float* __restrict__ hs,
                         const int* __restrict__ off, const int* __restrict__ csr,
                         const float* __restrict__ eps_p,
                         bf16_t* __restrict__ rst, int n) {
    int gid = blockIdx.x * blockDim.x + threadIdx.x;
    int u = __builtin_amdgcn_readfirstlane(gid >> 6);   // wave-uniform
    int lane = threadIdx.x & 63;
    if (u >= n) return;

    float acc0 = 0.f, acc1 = 0.f;
    int r0 = off[u], r1 = off[u + 1];
    unsigned loff = lane * 2u;

    for (int base = r0; base < r1; base += 64) {
        int m = r1 - base; if (m > 64) m = 64;           // uniform
        int li = (lane < m) ? lane : (m - 1);
        int iv = csr[base + li];                         // one coalesced load
        for (int c = 0; c < m; c += 16) {
            int s[16]; float sc[16]; unsigned v[16];
            #pragma unroll
            for (int t = 0; t < 16; t++)
                s[t] = __builtin_amdgcn_readlane(iv, c + t);   // SGPR indices
            #pragma unroll
            for (int t = 0; t < 16; t++)
                sc[t] = (c + t < m) ? hs[s[t]] : 0.f;          // scalar loads
            #pragma unroll
            for (int t = 0; t < 16; t++)
                v[t] = *(const unsigned short*)(h8 + (((unsigned)s[t] << 7) + loff));
            #pragma unroll
            for (int t = 0; t < 16; t++) {
                acc0 += (float)(int)(signed char)(v[t] & 0xffu) * sc[t];
                acc1 += (float)(int)(signed char)(v[t] >> 8) * sc[t];
            }
        }
    }

    float scu = hs[u] * (1.0f + eps_p[0]);
    unsigned vu = *(const unsigned short*)(h8 + (((unsigned)u << 7) + loff));
    float o0 = (float)(int)(signed char)(vu & 0xffu) * scu + acc0;
    float o1 = (float)(int)(signed char)(vu >> 8) * scu + acc1;

    int R = u >> 6, rr = u & 63;
    int i4 = rr >> 4, l15v = rr & 15;
    int ks = lane >> 4, quad = (lane >> 2) & 3, e2 = (lane & 3) * 2;
    size_t pos = (((size_t)R * 4 + ks) * 256 + (size_t)(i4 * 64 + quad * 16 + l15v)) * 8 + e2;
    *(unsigned int*)(rst + pos) =
        (unsigned int)f2b(o0) | ((unsigned int)f2b(o1) << 16);
}

// ---------------- layer-2 aggregation (u8 gather) ----------------

__global__ void k_agg_u8(const unsigned char* __restrict__ h8,
                         const float* __restrict__ hs,
                         const int* __restrict__ off, const int* __restrict__ csr,
                         const float* __restrict__ eps_p,
                         bf16_t* __restrict__ rst, int n) {
    int gid = blockIdx.x * blockDim.x + threadIdx.x;
    int u = __builtin_amdgcn_readfirstlane(gid >> 6);   // wave-uniform
    int lane = threadIdx.x & 63;
    if (u >= n) return;

    float acc[4] = {0.f, 0.f, 0.f, 0.f};
    int r0 = off[u], r1 = off[u + 1];
    unsigned loff = lane * 4u;

    for (int base = r0; base < r1; base += 64) {
        int m = r1 - base; if (m > 64) m = 64;           // uniform
        int li = (lane < m) ? lane : (m - 1);
        int iv = csr[base + li];                         // one coalesced load
        for (int c = 0; c < m; c += 16) {
            int s[16]; float sc[16]; unsigned int v[16];
            #pragma unroll
            for (int t = 0; t < 16; t++)
                s[t] = __builtin_amdgcn_readlane(iv, c + t);   // SGPR indices
            #pragma unroll
            for (int t = 0; t < 16; t++)
                sc[t] = (c + t < m) ? hs[s[t]] : 0.f;          // scalar loads
            #pragma unroll
            for (int t = 0; t < 16; t++)
                v[t] = *(const unsigned int*)(h8 + (((unsigned)s[t] << 8) + loff));
            #pragma unroll
            for (int t = 0; t < 16; t++) {
                acc[0] += (float)(v[t] & 0xffu) * sc[t];
                acc[1] += (float)((v[t] >> 8) & 0xffu) * sc[t];
                acc[2] += (float)((v[t] >> 16) & 0xffu) * sc[t];
                acc[3] += (float)(v[t] >> 24) * sc[t];
            }
        }
    }

    float ep = 1.0f + eps_p[0];
    unsigned int vu = *(const unsigned int*)(h8 + (((unsigned)u << 8) + loff));
    float scu = hs[u] * ep;
    float o0 = (float)(vu & 0xffu) * scu + acc[0];
    float o1 = (float)((vu >> 8) & 0xffu) * scu + acc[1];
    float o2 = (float)((vu >> 16) & 0xffu) * scu + acc[2];
    float o3 = (float)(vu >> 24) * scu + acc[3];
    uint2 ov;
    ov.x = (unsigned int)f2b(o0) | ((unsigned int)f2b(o1) << 16);
    ov.y = (unsigned int)f2b(o2) | ((unsigned int)f2b(o3) << 16);

    int R = u >> 6, rr = u & 63;
    int i4 = rr >> 4, l15v = rr & 15;
    int ks = lane >> 3, quad = (lane >> 1) & 3, e4 = (lane & 1) * 4;
    size_t pos = (((size_t)R * 8 + ks) * 256 + (size_t)(i4 * 64 + quad * 16 + l15v)) * 8 + e4;
    *(uint2*)(rst + pos) = ov;
}

// ---------------- fused 2-GEMM MLP, 64-row tile, 8 waves, 3 blocks/CU ----------------
// All operands in fragment-staging order -> linear gl_lds16 staging and
// conflict-free lane-linear LDS reads. SINGLE-buffered As (4KB) + Bs (16KB)
// + staged Ts (32KB) = 52.25 KB -> 3 blocks/CU (24 waves/CU): per-K-step
// latency (stage -> vmcnt(0)+barrier -> compute -> barrier) is covered by the
// other resident blocks' compute (TLP) instead of intra-block double-buffers.
// fc phase preloads FCt in two 16KB halves (2 stage-waits instead of 8).
// OUT8: u8 + per-row scale. FUSE_FC: phase 3 = h @ fc + bias -> fp32 out.

template <int K1, bool OUT8, bool FUSE_FC>
__global__ __launch_bounds__(512, 6) void k_mlp(
    const bf16_t* __restrict__ A, const bf16_t* __restrict__ W1t,
    const bf16_t* __restrict__ W2t, bf16_t* __restrict__ H,
    unsigned char* __restrict__ H8, float* __restrict__ Hs,
    const bf16_t* __restrict__ FCt, const float* __restrict__ fc_b,
    float* __restrict__ Cout, int M)
{
    constexpr int NS1 = K1 / 32;
    __shared__ __align__(16) bf16_t As[64 * 32];        // 4 KB, staged
    __shared__ __align__(16) bf16_t Bs[256 * 32];       // 16 KB, staged
    __shared__ __align__(16) bf16_t Ts[64 * 256];       // 32 KB, staged
    __shared__ int rmax[64];

    int tid = threadIdx.x;
    int wave = tid >> 6, lane = tid & 63;
    int l15 = lane & 15, quad = lane >> 4;
    int bm = blockIdx.x * 64;
    int wn = wave * 32;

    auto stageA = [&](int kstep) {
        if (tid < 256)
            gl_lds16(A + ((size_t)blockIdx.x * NS1 + kstep) * 2048 + tid * 8, &As[tid * 8]);
    };
    auto stageB = [&](const bf16_t* W, int kstep) {
        #pragma unroll
        for (int l = 0; l < 2; l++) {
            int c = l * 512 + tid;
            gl_lds16(W + ((size_t)kstep * 1024 + c) * 8, &Bs[c * 8]);
        }
    };

    // staged Ts element index for (row, col) in [64]x[256]
    auto ts_el = [&](int row, int col) {
        return ((col >> 5) * 4 + (row >> 4)) * 512 +
               ((((col >> 3) & 3) * 16) + (row & 15)) * 8 + (col & 7);
    };

    f32x4 acc[4][2];
    #pragma unroll
    for (int i = 0; i < 4; i++)
        #pragma unroll
        for (int j = 0; j < 2; j++) acc[i][j] = 0.f;

    // ---- phase 1: A (LDS) x W1t (LDS) ----
    #pragma unroll
    for (int k = 0; k < NS1; k++) {
        stageA(k); stageB(W1t, k);
        asm volatile("s_waitcnt vmcnt(0)" ::: "memory");
        __builtin_amdgcn_sched_barrier(0);
        __builtin_amdgcn_s_barrier();

        short8 af[4], bfv[2];
        #pragma unroll
        for (int i = 0; i < 4; i++)
            af[i] = *(const short8*)&As[(i * 64 + lane) * 8];
        #pragma unroll
        for (int j = 0; j < 2; j++)
            bfv[j] = *(const short8*)&Bs[((wave * 2 + j) * 64 + lane) * 8];

        #pragma unroll
        for (int i = 0; i < 4; i++)
            #pragma unroll
            for (int j = 0; j < 2; j++)
                acc[i][j] = __builtin_amdgcn_mfma_f32_16x16x32_bf16(af[i], bfv[j], acc[i][j], 0, 0, 0);

        // per-wave reads complete before its last MFMA issues (compiler
        // lgkmcnt), so barrier alone protects As/Bs for the next stage.
        __builtin_amdgcn_s_barrier();
    }

    // write relu(h1) into staged Ts
    #pragma unroll
    for (int i = 0; i < 4; i++)
        #pragma unroll
        for (int j = 0; j < 2; j++) {
            int col = wn + j * 16 + l15;
            #pragma unroll
            for (int r = 0; r < 4; r++) {
                int row = i * 16 + quad * 4 + r;
                Ts[ts_el(row, col)] = f2b(fmaxf(acc[i][j][r], 0.f));
            }
        }

    #pragma unroll
    for (int i = 0; i < 4; i++)
        #pragma unroll
        for (int j = 0; j < 2; j++) acc[i][j] = 0.f;
    __syncthreads();

    // ---- phase 2: relu(T) (LDS, staged) x W2t (LDS) ----
    #pragma unroll
    for (int k = 0; k < 8; k++) {
        stageB(W2t, k);
        asm volatile("s_waitcnt vmcnt(0)" ::: "memory");
        __builtin_amdgcn_sched_barrier(0);
        __builtin_amdgcn_s_barrier();

        short8 af[4], bfv[2];
        #pragma unroll
        for (int i = 0; i < 4; i++)
            af[i] = *(const short8*)&Ts[((k * 4 + i) * 64 + lane) * 8];
        #pragma unroll
        for (int j = 0; j < 2; j++)
            bfv[j] = *(const short8*)&Bs[((wave * 2 + j) * 64 + lane) * 8];

        #pragma unroll
        for (int i = 0; i < 4; i++)
            #pragma unroll
            for (int j = 0; j < 2; j++)
                acc[i][j] = __builtin_amdgcn_mfma_f32_16x16x32_bf16(af[i], bfv[j], acc[i][j], 0, 0, 0);

        __builtin_amdgcn_s_barrier();
    }

    if constexpr (OUT8) {
        if (tid < 64) rmax[tid] = 0;
        __syncthreads();
        #pragma unroll
        for (int i = 0; i < 4; i++)
            #pragma unroll
            for (int r = 0; r < 4; r++) {
                float m = 0.f;
                #pragma unroll
                for (int j = 0; j < 2; j++) m = fmaxf(m, acc[i][j][r]);
                atomicMax(&rmax[i * 16 + quad * 4 + r], __float_as_int(m));
            }
        __syncthreads();
        #pragma unroll
        for (int i = 0; i < 4; i++) {
            #pragma unroll
            for (int r = 0; r < 4; r++) {
                int row = i * 16 + quad * 4 + r;
                int rowg = bm + row;
                if (rowg >= M) continue;
                float rm = __int_as_float(rmax[row]);
                float inv = (rm > 0.f) ? 255.f / rm : 0.f;
                #pragma unroll
                for (int j = 0; j < 2; j++) {
                    int col = wn + j * 16 + l15;
                    float v = fmaxf(acc[i][j][r], 0.f);
                    unsigned q = (unsigned)(v * inv + 0.5f);
                    if (q > 255u) q = 255u;
                    H8[(size_t)rowg * 256 + col] = (unsigned char)q;
                }
                if (wave == 0 && l15 == 0)
                    Hs[rowg] = rm * (1.f / 255.f);
            }
        }
    } else if constexpr (FUSE_FC) {
        // write relu'd h tile back into staged Ts, then phase 3: out = h@fc + b
        #pragma unroll
        for (int i = 0; i < 4; i++)
            #pragma unroll
            for (int j = 0; j < 2; j++) {
                int col = wn + j * 16 + l15;
                #pragma unroll
                for (int r = 0; r < 4; r++) {
                    int row = i * 16 + quad * 4 + r;
                    Ts[ts_el(row, col)] = f2b(fmaxf(acc[i][j][r], 0.f));
                }
            }
        __syncthreads();

        f32x4 acc3[3];
        #pragma unroll
        for (int j = 0; j < 3; j++) acc3[j] = 0.f;

        // fc: preload FCt in two 16KB halves (4 ksteps each) into Bs
        #pragma unroll
        for (int hh = 0; hh < 2; hh++) {
            #pragma unroll
            for (int l = 0; l < 2; l++) {
                int c = l * 512 + tid;
                gl_lds16(FCt + ((size_t)hh * 1024 + c) * 8, &Bs[c * 8]);
            }
            asm volatile("s_waitcnt vmcnt(0)" ::: "memory");
            __builtin_amdgcn_sched_barrier(0);
            __builtin_amdgcn_s_barrier();

            if (tid < 256) {   // waves 0-3 compute rows [wave*16, wave*16+16)
                #pragma unroll
                for (int kk = 0; kk < 4; kk++) {
                    int k = hh * 4 + kk;
                    short8 af = *(const short8*)&Ts[((k * 4 + wave) * 64 + lane) * 8];
                    #pragma unroll
                    for (int j = 0; j < 3; j++) {
                        short8 bfv = *(const short8*)&Bs[((kk * 256) + j * 64 + lane) * 8];
                        acc3[j] = __builtin_amdgcn_mfma_f32_16x16x32_bf16(af, bfv, acc3[j], 0, 0, 0);
                    }
                }
            }
            __builtin_amdgcn_s_barrier();
        }

        if (tid < 256) {
            #pragma unroll
            for (int j = 0; j < 3; j++) {
                int col = j * 16 + l15;
                if (col >= DIM_C) continue;
                float bv = fc_b[col];
                #pragma unroll
                for (int r = 0; r < 4; r++) {
                    int rowg = bm + wave * 16 + quad * 4 + r;
                    if (rowg < M)
                        Cout[(size_t)rowg * DIM_C + col] = acc3[j][r] + bv;
                }
            }
        }
    } else {
        #pragma unroll
        for (int j = 0; j < 2; j++) {
            int col = wn + j * 16 + l15;
            #pragma unroll
            for (int i = 0; i < 4; i++) {
                #pragma unroll
                for (int r = 0; r < 4; r++) {
                    int rowg = bm + i * 16 + quad * 4 + r;
                    if (rowg < M)
                        H[(size_t)rowg * 256 + col] = f2b(fmaxf(acc[i][j][r], 0.f));
                }
            }
        }
    }
}

// ---------------- launch ----------------

static inline size_t rnd256(size_t x) { return (x + 255) & ~(size_t)255; }

extern "C" void kernel_launch(void* const* d_in, const int* in_sizes, int n_in,
                              void* d_out, int out_size, void* d_ws, size_t ws_size,
                              hipStream_t stream) {
    const float* x    = (const float*)d_in[0];
    const int*   src  = (const int*)d_in[1];
    const int*   dst  = (const int*)d_in[2];
    const float* eps1 = (const float*)d_in[3];
    const float* w1a  = (const float*)d_in[4];
    const float* w1b  = (const float*)d_in[5];
    const float* eps2 = (const float*)d_in[6];
    const float* w2a  = (const float*)d_in[7];
    const float* w2b  = (const float*)d_in[8];
    const float* fc_w = (const float*)d_in[9];
    const float* fc_b = (const float*)d_in[10];
    float* out = (float*)d_out;

    char* w = (char*)d_ws;
    int* off  = (int*)w; w += rnd256(sizeof(int) * (size_t)(N_NODES + 1));
    int* csr  = (int*)w; w += rnd256(sizeof(int) * (size_t)N_EDGES);
    int* cnt2  = (int*)w; w += rnd256(sizeof(int) * (size_t)NBLK * NB);
    int* basep = (int*)w; w += rnd256(sizeof(int) * (size_t)NBLK * NB);
    int* btot  = (int*)w; w += rnd256(sizeof(int) * 512);
    int* boff  = (int*)w; w += rnd256(sizeof(int) * (NB + 1));
    bf16_t* w1a_t = (bf16_t*)w; w += rnd256(2 * (size_t)DIM_H * DIM_IN);
    bf16_t* w1b_t = (bf16_t*)w; w += rnd256(2 * (size_t)DIM_H * DIM_H);
    bf16_t* w2a_t = (bf16_t*)w; w += rnd256(2 * (size_t)DIM_H * DIM_H);
    bf16_t* w2b_t = (bf16_t*)w; w += rnd256(2 * (size_t)DIM_H * DIM_H);
    bf16_t* fc_t  = (bf16_t*)w; w += rnd256(2 * (size_t)128 * DIM_H);
    signed char* x8 = (signed char*)w; w += rnd256((size_t)N_NODES * DIM_IN);
    float* xs = (float*)w; w += rnd256(sizeof(float) * (size_t)N_NODES);
    unsigned char* h8 = (unsigned char*)w; w += rnd256((size_t)N_NODES * DIM_H);
    float* hs = (float*)w; w += rnd256(sizeof(float) * (size_t)N_NODES);
    bf16_t* R12 = (bf16_t*)w; w += rnd256(2 * (size_t)NPAD * DIM_H);
    bf16_t* R3  = (bf16_t*)w; w += rnd256(2 * (size_t)NPAD * DIM_H);

    bf16_t* rst1 = R12;       // [1563][4][256][8] staging order, 25.6 MB
    int* ebuf = (int*)R3;     // 6.4 MB, dead before layer-2 agg writes R3
    int* ticket = btot + 500; // btot block has 512 ints, NB=391 used

    // ---- prep (hist + cvt + wcvt fused) ----
    k_prep<<<NBLK + CVT_BLOCKS + WCVT_BLOCKS, 256, 0, stream>>>(
        dst, cnt2, x, x8, xs, w1a, w1b, w2a, w2b, fc_w,
        w1a_t, w1b_t, w2a_t, w2b_t, fc_t, ticket);

    // ---- CSR build (scanA + scan2 fused via ticket) ----
    k_bscanA<<<NB, 512, 0, stream>>>(cnt2, basep, btot, ticket, boff);
    k_bscatter<<<NBLK, 256, 0, stream>>>(src, dst, basep, boff, ebuf, N_EDGES);
    k_build<<<NB, 256, 0, stream>>>(ebuf, boff, off, csr);

    const int agg_blocks = (N_NODES * 64 + 255) / 256;
    const int mlp_blocks = NPAD / 64;   // 1563

    // ---- layer 1: i8 agg -> MLP (u8 output + row scales) ----
    k_agg_i8<<<agg_blocks, 256, 0, stream>>>(x8, xs, off, csr, eps1, rst1, N_NODES);
    k_mlp<DIM_IN, true, false><<<mlp_blocks, 512, 0, stream>>>(
        rst1, w1a_t, w1b_t, nullptr, h8, hs, nullptr, nullptr, nullptr, N_NODES);

    // ---- layer 2: u8 agg -> MLP + fused fc (fp32 out) ----
    k_agg_u8<<<agg_blocks, 256, 0, stream>>>(h8, hs, off, csr, eps2, (bf16_t*)R3, N_NODES);
    k_mlp<DIM_H, false, true><<<mlp_blocks, 512, 0, stream>>>(
        (bf16_t*)R3, w2a_t, w2b_t, nullptr, nullptr, nullptr, fc_t, fc_b, out, N_NODES);
}

// Round 11
// 390.243 us; speedup vs baseline: 1.0591x; 1.0475x over previous
//
#include <hip/hip_runtime.h>

#define N_NODES 100000
#define NPAD    100032   // 1563 * 64, row-tile padded
#define N_EDGES 1600000
#define DIM_IN  128
#define DIM_H   256
#define DIM_C   40

#define NB   391     // buckets of 256 nodes
#define NBLK 391     // edge chunks of 4096
#define CHUNK 4096
#define ECAP 6144    // LDS edge-cache capacity in k_build (ints)

#define CVT_BLOCKS 25000   // N_NODES*64/256
#define WCVT_BLOCKS 1280   // 5 * 256

typedef unsigned short bf16_t;
typedef __attribute__((ext_vector_type(8))) short short8;
typedef __attribute__((ext_vector_type(4))) float f32x4;

__device__ __forceinline__ bf16_t f2b(float f) {
    unsigned int u = __float_as_uint(f);
    unsigned int r = (u + 0x7fffu + ((u >> 16) & 1u)) >> 16;
    return (bf16_t)r;
}

__device__ __forceinline__ void gl_lds16(const void* gsrc, void* ldst) {
    __builtin_amdgcn_global_load_lds(
        (const __attribute__((address_space(1))) void*)gsrc,
        (__attribute__((address_space(3))) void*)ldst,
        16, 0, 0);
}

// ---------------- fused prep: bhist + x->i8 cvt + weight cvt ----------------
// Weights stored in MFMA fragment-staging order: [kstep][chunk][8 bf16],
// chunk = tt*64 + quad*16 + l15 (tt = 16-row tile of B^T). A fragment read is
// then a coalesced 16B/lane global load: bfv[j] = W[(kstep*1024 + c)*8].

__global__ __launch_bounds__(256) void k_prep(
    const int* __restrict__ dst, int* __restrict__ cnt2,
    const float* __restrict__ x, signed char* __restrict__ x8, float* __restrict__ xs,
    const float* __restrict__ w1a, const float* __restrict__ w1b,
    const float* __restrict__ w2a, const float* __restrict__ w2b,
    const float* __restrict__ fcw,
    bf16_t* __restrict__ o1a, bf16_t* __restrict__ o1b,
    bf16_t* __restrict__ o2a, bf16_t* __restrict__ o2b, bf16_t* __restrict__ ofc,
    int* __restrict__ ticket)
{
    __shared__ int h[NB];
    int blk = blockIdx.x, t = threadIdx.x;

    if (blk < NBLK) {
        if (blk == 0 && t == 0) *ticket = 0;
        for (int i = t; i < NB; i += 256) h[i] = 0;
        __syncthreads();
        int base = blk * CHUNK;
        int end = min(base + CHUNK, N_EDGES);
        for (int i = base + t; i < end; i += 256)
            atomicAdd(&h[dst[i] >> 8], 1);
        __syncthreads();
        for (int i = t; i < NB; i += 256) cnt2[blk * NB + i] = h[i];
        return;
    }
    blk -= NBLK;

    if (blk < CVT_BLOCKS) {
        int gid = blk * 256 + t;
        int u = gid >> 6, lane = gid & 63;
        float2 v = *(const float2*)(x + (size_t)u * 128 + lane * 2);
        float m = fmaxf(fabsf(v.x), fabsf(v.y));
        #pragma unroll
        for (int d = 1; d < 64; d <<= 1)
            m = fmaxf(m, __shfl_xor(m, d, 64));
        float inv = (m > 0.f) ? 127.f / m : 0.f;
        int q0 = (int)rintf(v.x * inv);
        int q1 = (int)rintf(v.y * inv);
        unsigned short pk = (unsigned short)((q0 & 0xff) | ((q1 & 0xff) << 8));
        *(unsigned short*)(x8 + ((unsigned)u << 7) + lane * 2) = pk;
        if (lane == 0) xs[u] = (m > 0.f) ? m * (1.f / 127.f) : 0.f;
        return;
    }
    blk -= CVT_BLOCKS;

    // weight cvt into staging order. r = blk>>8, 256 blocks per matrix.
    int r = blk >> 8;
    int idx = (blk & 255) * 256 + t;
    const float* in; bf16_t* out; int K, N, Npad;
    switch (r) {
        case 0: in = w1a; out = o1a; K = 128; N = 256; Npad = 256; break;
        case 1: in = w1b; out = o1b; K = 256; N = 256; Npad = 256; break;
        case 2: in = w2a; out = o2a; K = 256; N = 256; Npad = 256; break;
        case 3: in = w2b; out = o2b; K = 256; N = 256; Npad = 256; break;
        default: in = fcw; out = ofc; K = 256; N = 40;  Npad = 64;  break;
    }
    if (idx >= Npad * K) return;
    int n = idx / K, k = idx - n * K;
    float v = (n < N) ? in[(size_t)k * N + n] : 0.f;
    int kstep = k >> 5, quad = (k >> 3) & 3, e = k & 7;
    int tt = n >> 4, l15 = n & 15;
    size_t opos = (size_t)kstep * (Npad * 32) + ((size_t)(tt * 64 + quad * 16 + l15)) * 8 + e;
    out[opos] = f2b(v);
}

// ---------------- CSR build ----------------

__global__ void k_bscanA(const int* __restrict__ cnt2, int* __restrict__ basep,
                         int* __restrict__ btot, int* __restrict__ ticket,
                         int* __restrict__ boff) {
    __shared__ int s[512];
    __shared__ int isLast;
    int t = threadIdx.x, b = blockIdx.x;
    int v = (t < NBLK) ? cnt2[t * NB + b] : 0;
    s[t] = v;
    __syncthreads();
    #pragma unroll
    for (int d = 1; d < 512; d <<= 1) {
        int tv = (t >= d) ? s[t - d] : 0;
        __syncthreads();
        s[t] += tv;
        __syncthreads();
    }
    if (t < NBLK) basep[t * NB + b] = s[t] - v;
    if (t == 511) atomicExch(&btot[b], s[511]);
    __syncthreads();
    if (t == 0) {
        __threadfence();
        int old = atomicAdd(ticket, 1);
        isLast = (old == NB - 1);
    }
    __syncthreads();
    if (!isLast) return;

    __threadfence();
    int v2 = (t < NB) ? atomicAdd(&btot[t], 0) : 0;
    s[t] = v2;
    __syncthreads();
    #pragma unroll
    for (int d = 1; d < 512; d <<= 1) {
        int tv = (t >= d) ? s[t - d] : 0;
        __syncthreads();
        s[t] += tv;
        __syncthreads();
    }
    if (t < NB) boff[t] = s[t] - v2;
    if (t == NB - 1) boff[NB] = s[t];
}

__global__ void k_bscatter(const int* __restrict__ src, const int* __restrict__ dst,
                           const int* __restrict__ basep, const int* __restrict__ boff,
                           int* __restrict__ ebuf, int e) {
    __shared__ int cur[NB];
    int t = threadIdx.x, blk = blockIdx.x;
    for (int i = t; i < NB; i += 256) cur[i] = basep[blk * NB + i] + boff[i];
    __syncthreads();
    int base = blk * CHUNK;
    int end = min(base + CHUNK, e);
    for (int i = base + t; i < end; i += 256) {
        int sv = src[i], dv = dst[i];
        int pos = atomicAdd(&cur[dv >> 8], 1);
        ebuf[pos] = sv | ((dv & 255) << 24);
    }
}

__global__ __launch_bounds__(256) void k_build(const int* __restrict__ ebuf,
                                               const int* __restrict__ boff,
                                               int* __restrict__ off,
                                               int* __restrict__ csr) {
    __shared__ int ec[ECAP];
    __shared__ int h[256];
    __shared__ int cur[256];
    int t = threadIdx.x, b = blockIdx.x;
    int node0 = b << 8;
    int e0 = boff[b], e1 = boff[b + 1];
    int ne = e1 - e0;
    bool fits = (ne <= ECAP);
    h[t] = 0;
    __syncthreads();
    if (fits) {
        for (int i = t; i < ne; i += 256) {
            int p = ebuf[e0 + i];
            ec[i] = p;
            atomicAdd(&h[(unsigned)p >> 24], 1);
        }
    } else {
        for (int i = t; i < ne; i += 256)
            atomicAdd(&h[(unsigned)ebuf[e0 + i] >> 24], 1);
    }
    __syncthreads();
    int mydeg = h[t];
    #pragma unroll
    for (int d = 1; d < 256; d <<= 1) {
        int tv = (t >= d) ? h[t - d] : 0;
        __syncthreads();
        h[t] += tv;
        __syncthreads();
    }
    int node = node0 + t;
    if (node < N_NODES) off[node + 1] = e0 + h[t];
    if (b == 0 && t == 0) off[0] = 0;
    cur[t] = e0 + h[t] - mydeg;
    __syncthreads();
    if (fits) {
        for (int i = t; i < ne; i += 256) {
            int p = ec[i];
            int pos = atomicAdd(&cur[(unsigned)p >> 24], 1);
            csr[pos] = p & 0xFFFFFF;
        }
    } else {
        for (int i = t; i < ne; i += 256) {
            int p = ebuf[e0 + i];
            int pos = atomicAdd(&cur[(unsigned)p >> 24], 1);
            csr[pos] = p & 0xFFFFFF;
        }
    }
}

// ---------------- layer-1 aggregation (i8 gather) ----------------
// Gather loop untouched (frozen, miss-path floor). Epilogue writes rst in
// A-fragment-staging order.

__global__ void k_agg_i8(const signed char* __restrict__ h8, const float* __restrict__ hs,
                         const int* __restrict__ off, const int* __restrict__ csr,
                         const float* __restrict__ eps_p,
                         bf16_t* __restrict__ rst, int n) {
    int gid = blockIdx.x * blockDim.x + threadIdx.x;
    int u = __builtin_amdgcn_readfirstlane(gid >> 6);   // wave-uniform
    int lane = threadIdx.x & 63;
    if (u >= n) return;

    float acc0 = 0.f, acc1 = 0.f;
    int r0 = off[u], r1 = off[u + 1];
    unsigned loff = lane * 2u;

    for (int base = r0; base < r1; base += 64) {
        int m = r1 - base; if (m > 64) m = 64;           // uniform
        int li = (lane < m) ? lane : (m - 1);
        int iv = csr[base + li];                         // one coalesced load
        for (int c = 0; c < m; c += 16) {
            int s[16]; float sc[16]; unsigned v[16];
            #pragma unroll
            for (int t = 0; t < 16; t++)
                s[t] = __builtin_amdgcn_readlane(iv, c + t);   // SGPR indices
            #pragma unroll
            for (int t = 0; t < 16; t++)
                sc[t] = (c + t < m) ? hs[s[t]] : 0.f;          // scalar loads
            #pragma unroll
            for (int t = 0; t < 16; t++)
                v[t] = *(const unsigned short*)(h8 + (((unsigned)s[t] << 7) + loff));
            #pragma unroll
            for (int t = 0; t < 16; t++) {
                acc0 += (float)(int)(signed char)(v[t] & 0xffu) * sc[t];
                acc1 += (float)(int)(signed char)(v[t] >> 8) * sc[t];
            }
        }
    }

    float scu = hs[u] * (1.0f + eps_p[0]);
    unsigned vu = *(const unsigned short*)(h8 + (((unsigned)u << 7) + loff));
    float o0 = (float)(int)(signed char)(vu & 0xffu) * scu + acc0;
    float o1 = (float)(int)(signed char)(vu >> 8) * scu + acc1;

    int R = u >> 6, rr = u & 63;
    int i4 = rr >> 4, l15v = rr & 15;
    int ks = lane >> 4, quad = (lane >> 2) & 3, e2 = (lane & 3) * 2;
    size_t pos = (((size_t)R * 4 + ks) * 256 + (size_t)(i4 * 64 + quad * 16 + l15v)) * 8 + e2;
    *(unsigned int*)(rst + pos) =
        (unsigned int)f2b(o0) | ((unsigned int)f2b(o1) << 16);
}

// ---------------- layer-2 aggregation (u8 gather) ----------------

__global__ void k_agg_u8(const unsigned char* __restrict__ h8,
                         const float* __restrict__ hs,
                         const int* __restrict__ off, const int* __restrict__ csr,
                         const float* __restrict__ eps_p,
                         bf16_t* __restrict__ rst, int n) {
    int gid = blockIdx.x * blockDim.x + threadIdx.x;
    int u = __builtin_amdgcn_readfirstlane(gid >> 6);   // wave-uniform
    int lane = threadIdx.x & 63;
    if (u >= n) return;

    float acc[4] = {0.f, 0.f, 0.f, 0.f};
    int r0 = off[u], r1 = off[u + 1];
    unsigned loff = lane * 4u;

    for (int base = r0; base < r1; base += 64) {
        int m = r1 - base; if (m > 64) m = 64;           // uniform
        int li = (lane < m) ? lane : (m - 1);
        int iv = csr[base + li];                         // one coalesced load
        for (int c = 0; c < m; c += 16) {
            int s[16]; float sc[16]; unsigned int v[16];
            #pragma unroll
            for (int t = 0; t < 16; t++)
                s[t] = __builtin_amdgcn_readlane(iv, c + t);   // SGPR indices
            #pragma unroll
            for (int t = 0; t < 16; t++)
                sc[t] = (c + t < m) ? hs[s[t]] : 0.f;          // scalar loads
            #pragma unroll
            for (int t = 0; t < 16; t++)
                v[t] = *(const unsigned int*)(h8 + (((unsigned)s[t] << 8) + loff));
            #pragma unroll
            for (int t = 0; t < 16; t++) {
                acc[0] += (float)(v[t] & 0xffu) * sc[t];
                acc[1] += (float)((v[t] >> 8) & 0xffu) * sc[t];
                acc[2] += (float)((v[t] >> 16) & 0xffu) * sc[t];
                acc[3] += (float)(v[t] >> 24) * sc[t];
            }
        }
    }

    float ep = 1.0f + eps_p[0];
    unsigned int vu = *(const unsigned int*)(h8 + (((unsigned)u << 8) + loff));
    float scu = hs[u] * ep;
    float o0 = (float)(vu & 0xffu) * scu + acc[0];
    float o1 = (float)((vu >> 8) & 0xffu) * scu + acc[1];
    float o2 = (float)((vu >> 16) & 0xffu) * scu + acc[2];
    float o3 = (float)(vu >> 24) * scu + acc[3];
    uint2 ov;
    ov.x = (unsigned int)f2b(o0) | ((unsigned int)f2b(o1) << 16);
    ov.y = (unsigned int)f2b(o2) | ((unsigned int)f2b(o3) << 16);

    int R = u >> 6, rr = u & 63;
    int i4 = rr >> 4, l15v = rr & 15;
    int ks = lane >> 3, quad = (lane >> 1) & 3, e4 = (lane & 1) * 4;
    size_t pos = (((size_t)R * 8 + ks) * 256 + (size_t)(i4 * 64 + quad * 16 + l15v)) * 8 + e4;
    *(uint2*)(rst + pos) = ov;
}

// ---------------- fused 2-GEMM MLP: global-direct fragments ----------------
// R9 diagnosis: the per-CU LDS pipe (staging writes + ds_read_b128s + scalar
// Ts writes) is the floor. Fix: A and W are already fragment-staged in global
// memory, so read af/bfv DIRECTLY global->VGPR (coalesced 16B/lane; weights
// are L2-resident). No As/Bs LDS, no gl_lds16, NO in-loop barriers. LDS holds
// only Ts (32 KB, cross-wave h1) with 3 syncthreads total. 256 thr, 4 blk/CU.
// NOTE element strides: A is [block][NS1][2048 elems] -> k*2048 + chunk*8;
// W is [kstep][1024 chunks][8] -> (k*1024 + chunk)*8;  FCt -> (k*256 + chunk)*8.
// (R10 bug: W kstep term was not scaled by 8.)
// OUT8: u8 + per-row scale. FUSE_FC: phase 3 = h @ fc + bias -> fp32 out.

template <int K1, bool OUT8, bool FUSE_FC>
__global__ __launch_bounds__(256, 4) void k_mlp(
    const bf16_t* __restrict__ A, const bf16_t* __restrict__ W1t,
    const bf16_t* __restrict__ W2t, bf16_t* __restrict__ H,
    unsigned char* __restrict__ H8, float* __restrict__ Hs,
    const bf16_t* __restrict__ FCt, const float* __restrict__ fc_b,
    float* __restrict__ Cout, int M)
{
    constexpr int NS1 = K1 / 32;
    __shared__ __align__(16) bf16_t Ts[64 * 256];       // 32 KB, staged layout
    __shared__ int rmax[64];

    int tid = threadIdx.x;
    int wave = tid >> 6, lane = tid & 63;
    int l15 = lane & 15, quad = lane >> 4;
    int bm = blockIdx.x * 64;
    int wn = wave * 64;   // wave owns 64 cols (4 col-tiles)

    // staged Ts element index for (row, col) in [64]x[256]
    auto ts_el = [&](int row, int col) {
        return ((col >> 5) * 4 + (row >> 4)) * 512 +
               ((((col >> 3) & 3) * 16) + (row & 15)) * 8 + (col & 7);
    };

    f32x4 acc[4][4];
    #pragma unroll
    for (int i = 0; i < 4; i++)
        #pragma unroll
        for (int j = 0; j < 4; j++) acc[i][j] = 0.f;

    // ---- phase 1: A (global) x W1t (global), no LDS, no barriers ----
    const bf16_t* Ab = A + (size_t)blockIdx.x * NS1 * 2048;
    #pragma unroll
    for (int k = 0; k < NS1; k++) {
        short8 af[4], bfv[4];
        #pragma unroll
        for (int i = 0; i < 4; i++)
            af[i] = *(const short8*)(Ab + ((size_t)k * 2048 + (i * 64 + lane) * 8));
        #pragma unroll
        for (int j = 0; j < 4; j++)
            bfv[j] = *(const short8*)(W1t + ((size_t)k * 1024 + (wave * 4 + j) * 64 + lane) * 8);
        #pragma unroll
        for (int i = 0; i < 4; i++)
            #pragma unroll
            for (int j = 0; j < 4; j++)
                acc[i][j] = __builtin_amdgcn_mfma_f32_16x16x32_bf16(af[i], bfv[j], acc[i][j], 0, 0, 0);
    }

    // write relu(h1) into staged Ts
    #pragma unroll
    for (int i = 0; i < 4; i++)
        #pragma unroll
        for (int j = 0; j < 4; j++) {
            int col = wn + j * 16 + l15;
            #pragma unroll
            for (int r = 0; r < 4; r++) {
                int row = i * 16 + quad * 4 + r;
                Ts[ts_el(row, col)] = f2b(fmaxf(acc[i][j][r], 0.f));
            }
        }

    #pragma unroll
    for (int i = 0; i < 4; i++)
        #pragma unroll
        for (int j = 0; j < 4; j++) acc[i][j] = 0.f;
    __syncthreads();

    // ---- phase 2: relu(T) (LDS, staged) x W2t (global) ----
    #pragma unroll
    for (int k = 0; k < 8; k++) {
        short8 af[4], bfv[4];
        #pragma unroll
        for (int i = 0; i < 4; i++)
            af[i] = *(const short8*)&Ts[((k * 4 + i) * 64 + lane) * 8];
        #pragma unroll
        for (int j = 0; j < 4; j++)
            bfv[j] = *(const short8*)(W2t + ((size_t)k * 1024 + (wave * 4 + j) * 64 + lane) * 8);
        #pragma unroll
        for (int i = 0; i < 4; i++)
            #pragma unroll
            for (int j = 0; j < 4; j++)
                acc[i][j] = __builtin_amdgcn_mfma_f32_16x16x32_bf16(af[i], bfv[j], acc[i][j], 0, 0, 0);
    }

    if constexpr (OUT8) {
        if (tid < 64) rmax[tid] = 0;
        __syncthreads();
        #pragma unroll
        for (int i = 0; i < 4; i++)
            #pragma unroll
            for (int r = 0; r < 4; r++) {
                float m = 0.f;
                #pragma unroll
                for (int j = 0; j < 4; j++) m = fmaxf(m, acc[i][j][r]);
                atomicMax(&rmax[i * 16 + quad * 4 + r], __float_as_int(m));
            }
        __syncthreads();
        #pragma unroll
        for (int i = 0; i < 4; i++) {
            #pragma unroll
            for (int r = 0; r < 4; r++) {
                int row = i * 16 + quad * 4 + r;
                int rowg = bm + row;
                if (rowg >= M) continue;
                float rm = __int_as_float(rmax[row]);
                float inv = (rm > 0.f) ? 255.f / rm : 0.f;
                #pragma unroll
                for (int j = 0; j < 4; j++) {
                    int col = wn + j * 16 + l15;
                    float v = fmaxf(acc[i][j][r], 0.f);
                    unsigned q = (unsigned)(v * inv + 0.5f);
                    if (q > 255u) q = 255u;
                    H8[(size_t)rowg * 256 + col] = (unsigned char)q;
                }
                if (wave == 0 && l15 == 0)
                    Hs[rowg] = rm * (1.f / 255.f);
            }
        }
    } else if constexpr (FUSE_FC) {
        // protect phase-2's Ts readers, then overwrite Ts with relu(h2)
        __syncthreads();
        #pragma unroll
        for (int i = 0; i < 4; i++)
            #pragma unroll
            for (int j = 0; j < 4; j++) {
                int col = wn + j * 16 + l15;
                #pragma unroll
                for (int r = 0; r < 4; r++) {
                    int row = i * 16 + quad * 4 + r;
                    Ts[ts_el(row, col)] = f2b(fmaxf(acc[i][j][r], 0.f));
                }
            }
        __syncthreads();

        // phase 3: each wave computes rows [wave*16, wave*16+16), cols 0..47
        f32x4 acc3[3];
        #pragma unroll
        for (int j = 0; j < 3; j++) acc3[j] = 0.f;

        #pragma unroll
        for (int k = 0; k < 8; k++) {
            short8 af = *(const short8*)&Ts[((k * 4 + wave) * 64 + lane) * 8];
            #pragma unroll
            for (int j = 0; j < 3; j++) {
                short8 bfv = *(const short8*)(FCt + ((size_t)k * 256 + j * 64 + lane) * 8);
                acc3[j] = __builtin_amdgcn_mfma_f32_16x16x32_bf16(af, bfv, acc3[j], 0, 0, 0);
            }
        }

        #pragma unroll
        for (int j = 0; j < 3; j++) {
            int col = j * 16 + l15;
            if (col >= DIM_C) continue;
            float bv = fc_b[col];
            #pragma unroll
            for (int r = 0; r < 4; r++) {
                int rowg = bm + wave * 16 + quad * 4 + r;
                if (rowg < M)
                    Cout[(size_t)rowg * DIM_C + col] = acc3[j][r] + bv;
            }
        }
    } else {
        #pragma unroll
        for (int j = 0; j < 4; j++) {
            int col = wn + j * 16 + l15;
            #pragma unroll
            for (int i = 0; i < 4; i++) {
                #pragma unroll
                for (int r = 0; r < 4; r++) {
                    int rowg = bm + i * 16 + quad * 4 + r;
                    if (rowg < M)
                        H[(size_t)rowg * 256 + col] = f2b(fmaxf(acc[i][j][r], 0.f));
                }
            }
        }
    }
}

// ---------------- launch ----------------

static inline size_t rnd256(size_t x) { return (x + 255) & ~(size_t)255; }

extern "C" void kernel_launch(void* const* d_in, const int* in_sizes, int n_in,
                              void* d_out, int out_size, void* d_ws, size_t ws_size,
                              hipStream_t stream) {
    const float* x    = (const float*)d_in[0];
    const int*   src  = (const int*)d_in[1];
    const int*   dst  = (const int*)d_in[2];
    const float* eps1 = (const float*)d_in[3];
    const float* w1a  = (const float*)d_in[4];
    const float* w1b  = (const float*)d_in[5];
    const float* eps2 = (const float*)d_in[6];
    const float* w2a  = (const float*)d_in[7];
    const float* w2b  = (const float*)d_in[8];
    const float* fc_w = (const float*)d_in[9];
    const float* fc_b = (const float*)d_in[10];
    float* out = (float*)d_out;

    char* w = (char*)d_ws;
    int* off  = (int*)w; w += rnd256(sizeof(int) * (size_t)(N_NODES + 1));
    int* csr  = (int*)w; w += rnd256(sizeof(int) * (size_t)N_EDGES);
    int* cnt2  = (int*)w; w += rnd256(sizeof(int) * (size_t)NBLK * NB);
    int* basep = (int*)w; w += rnd256(sizeof(int) * (size_t)NBLK * NB);
    int* btot  = (int*)w; w += rnd256(sizeof(int) * 512);
    int* boff  = (int*)w; w += rnd256(sizeof(int) * (NB + 1));
    bf16_t* w1a_t = (bf16_t*)w; w += rnd256(2 * (size_t)DIM_H * DIM_IN);
    bf16_t* w1b_t = (bf16_t*)w; w += rnd256(2 * (size_t)DIM_H * DIM_H);
    bf16_t* w2a_t = (bf16_t*)w; w += rnd256(2 * (size_t)DIM_H * DIM_H);
    bf16_t* w2b_t = (bf16_t*)w; w += rnd256(2 * (size_t)DIM_H * DIM_H);
    bf16_t* fc_t  = (bf16_t*)w; w += rnd256(2 * (size_t)128 * DIM_H);
    signed char* x8 = (signed char*)w; w += rnd256((size_t)N_NODES * DIM_IN);
    float* xs = (float*)w; w += rnd256(sizeof(float) * (size_t)N_NODES);
    unsigned char* h8 = (unsigned char*)w; w += rnd256((size_t)N_NODES * DIM_H);
    float* hs = (float*)w; w += rnd256(sizeof(float) * (size_t)N_NODES);
    bf16_t* R12 = (bf16_t*)w; w += rnd256(2 * (size_t)NPAD * DIM_H);
    bf16_t* R3  = (bf16_t*)w; w += rnd256(2 * (size_t)NPAD * DIM_H);

    bf16_t* rst1 = R12;       // [1563][4][256][8] staging order, 25.6 MB
    int* ebuf = (int*)R3;     // 6.4 MB, dead before layer-2 agg writes R3
    int* ticket = btot + 500; // btot block has 512 ints, NB=391 used

    // ---- prep (hist + cvt + wcvt fused) ----
    k_prep<<<NBLK + CVT_BLOCKS + WCVT_BLOCKS, 256, 0, stream>>>(
        dst, cnt2, x, x8, xs, w1a, w1b, w2a, w2b, fc_w,
        w1a_t, w1b_t, w2a_t, w2b_t, fc_t, ticket);

    // ---- CSR build (scanA + scan2 fused via ticket) ----
    k_bscanA<<<NB, 512, 0, stream>>>(cnt2, basep, btot, ticket, boff);
    k_bscatter<<<NBLK, 256, 0, stream>>>(src, dst, basep, boff, ebuf, N_EDGES);
    k_build<<<NB, 256, 0, stream>>>(ebuf, boff, off, csr);

    const int agg_blocks = (N_NODES * 64 + 255) / 256;
    const int mlp_blocks = NPAD / 64;   // 1563

    // ---- layer 1: i8 agg -> MLP (u8 output + row scales) ----
    k_agg_i8<<<agg_blocks, 256, 0, stream>>>(x8, xs, off, csr, eps1, rst1, N_NODES);
    k_mlp<DIM_IN, true, false><<<mlp_blocks, 256, 0, stream>>>(
        rst1, w1a_t, w1b_t, nullptr, h8, hs, nullptr, nullptr, nullptr, N_NODES);

    // ---- layer 2: u8 agg -> MLP + fused fc (fp32 out) ----
    k_agg_u8<<<agg_blocks, 256, 0, stream>>>(h8, hs, off, csr, eps2, (bf16_t*)R3, N_NODES);
    k_mlp<DIM_H, false, true><<<mlp_blocks, 256, 0, stream>>>(
        (bf16_t*)R3, w2a_t, w2b_t, nullptr, nullptr, nullptr, fc_t, fc_b, out, N_NODES);
}

// Round 12
// 381.691 us; speedup vs baseline: 1.0829x; 1.0224x over previous
//
#include <hip/hip_runtime.h>

#define N_NODES 100000
#define NPAD    100032   // 1563 * 64, row-tile padded
#define N_EDGES 1600000
#define DIM_IN  128
#define DIM_H   256
#define DIM_C   40

#define NB   391     // buckets of 256 nodes
#define NBLK 391     // edge chunks of 4096
#define CHUNK 4096
#define ECAP 6144    // LDS edge-cache capacity in k_build (ints)

#define CVT_BLOCKS 25000   // N_NODES*64/256
#define WCVT_BLOCKS 1280   // 5 * 256

typedef unsigned short bf16_t;
typedef __attribute__((ext_vector_type(8))) short short8;
typedef __attribute__((ext_vector_type(4))) float f32x4;

__device__ __forceinline__ bf16_t f2b(float f) {
    unsigned int u = __float_as_uint(f);
    unsigned int r = (u + 0x7fffu + ((u >> 16) & 1u)) >> 16;
    return (bf16_t)r;
}

__device__ __forceinline__ void gl_lds16(const void* gsrc, void* ldst) {
    __builtin_amdgcn_global_load_lds(
        (const __attribute__((address_space(1))) void*)gsrc,
        (__attribute__((address_space(3))) void*)ldst,
        16, 0, 0);
}

// ---------------- fused prep: bhist + x->i8 cvt + weight cvt ----------------
// Weights stored in MFMA fragment-staging order: [kstep][chunk][8 bf16],
// chunk = tt*64 + quad*16 + l15 (tt = 16-row tile of B^T). A fragment read is
// then a coalesced 16B/lane global load: bfv[j] = W[(kstep*1024 + c)*8].

__global__ __launch_bounds__(256) void k_prep(
    const int* __restrict__ dst, int* __restrict__ cnt2,
    const float* __restrict__ x, signed char* __restrict__ x8, float* __restrict__ xs,
    const float* __restrict__ w1a, const float* __restrict__ w1b,
    const float* __restrict__ w2a, const float* __restrict__ w2b,
    const float* __restrict__ fcw,
    bf16_t* __restrict__ o1a, bf16_t* __restrict__ o1b,
    bf16_t* __restrict__ o2a, bf16_t* __restrict__ o2b, bf16_t* __restrict__ ofc,
    int* __restrict__ ticket)
{
    __shared__ int h[NB];
    int blk = blockIdx.x, t = threadIdx.x;

    if (blk < NBLK) {
        if (blk == 0 && t == 0) *ticket = 0;
        for (int i = t; i < NB; i += 256) h[i] = 0;
        __syncthreads();
        int base = blk * CHUNK;
        int end = min(base + CHUNK, N_EDGES);
        for (int i = base + t; i < end; i += 256)
            atomicAdd(&h[dst[i] >> 8], 1);
        __syncthreads();
        for (int i = t; i < NB; i += 256) cnt2[blk * NB + i] = h[i];
        return;
    }
    blk -= NBLK;

    if (blk < CVT_BLOCKS) {
        int gid = blk * 256 + t;
        int u = gid >> 6, lane = gid & 63;
        float2 v = *(const float2*)(x + (size_t)u * 128 + lane * 2);
        float m = fmaxf(fabsf(v.x), fabsf(v.y));
        #pragma unroll
        for (int d = 1; d < 64; d <<= 1)
            m = fmaxf(m, __shfl_xor(m, d, 64));
        float inv = (m > 0.f) ? 127.f / m : 0.f;
        int q0 = (int)rintf(v.x * inv);
        int q1 = (int)rintf(v.y * inv);
        unsigned short pk = (unsigned short)((q0 & 0xff) | ((q1 & 0xff) << 8));
        *(unsigned short*)(x8 + ((unsigned)u << 7) + lane * 2) = pk;
        if (lane == 0) xs[u] = (m > 0.f) ? m * (1.f / 127.f) : 0.f;
        return;
    }
    blk -= CVT_BLOCKS;

    // weight cvt into staging order. r = blk>>8, 256 blocks per matrix.
    int r = blk >> 8;
    int idx = (blk & 255) * 256 + t;
    const float* in; bf16_t* out; int K, N, Npad;
    switch (r) {
        case 0: in = w1a; out = o1a; K = 128; N = 256; Npad = 256; break;
        case 1: in = w1b; out = o1b; K = 256; N = 256; Npad = 256; break;
        case 2: in = w2a; out = o2a; K = 256; N = 256; Npad = 256; break;
        case 3: in = w2b; out = o2b; K = 256; N = 256; Npad = 256; break;
        default: in = fcw; out = ofc; K = 256; N = 40;  Npad = 64;  break;
    }
    if (idx >= Npad * K) return;
    int n = idx / K, k = idx - n * K;
    float v = (n < N) ? in[(size_t)k * N + n] : 0.f;
    int kstep = k >> 5, quad = (k >> 3) & 3, e = k & 7;
    int tt = n >> 4, l15 = n & 15;
    size_t opos = (size_t)kstep * (Npad * 32) + ((size_t)(tt * 64 + quad * 16 + l15)) * 8 + e;
    out[opos] = f2b(v);
}

// ---------------- CSR build ----------------

__global__ void k_bscanA(const int* __restrict__ cnt2, int* __restrict__ basep,
                         int* __restrict__ btot, int* __restrict__ ticket,
                         int* __restrict__ boff) {
    __shared__ int s[512];
    __shared__ int isLast;
    int t = threadIdx.x, b = blockIdx.x;
    int v = (t < NBLK) ? cnt2[t * NB + b] : 0;
    s[t] = v;
    __syncthreads();
    #pragma unroll
    for (int d = 1; d < 512; d <<= 1) {
        int tv = (t >= d) ? s[t - d] : 0;
        __syncthreads();
        s[t] += tv;
        __syncthreads();
    }
    if (t < NBLK) basep[t * NB + b] = s[t] - v;
    if (t == 511) atomicExch(&btot[b], s[511]);
    __syncthreads();
    if (t == 0) {
        __threadfence();
        int old = atomicAdd(ticket, 1);
        isLast = (old == NB - 1);
    }
    __syncthreads();
    if (!isLast) return;

    __threadfence();
    int v2 = (t < NB) ? atomicAdd(&btot[t], 0) : 0;
    s[t] = v2;
    __syncthreads();
    #pragma unroll
    for (int d = 1; d < 512; d <<= 1) {
        int tv = (t >= d) ? s[t - d] : 0;
        __syncthreads();
        s[t] += tv;
        __syncthreads();
    }
    if (t < NB) boff[t] = s[t] - v2;
    if (t == NB - 1) boff[NB] = s[t];
}

__global__ void k_bscatter(const int* __restrict__ src, const int* __restrict__ dst,
                           const int* __restrict__ basep, const int* __restrict__ boff,
                           int* __restrict__ ebuf, int e) {
    __shared__ int cur[NB];
    int t = threadIdx.x, blk = blockIdx.x;
    for (int i = t; i < NB; i += 256) cur[i] = basep[blk * NB + i] + boff[i];
    __syncthreads();
    int base = blk * CHUNK;
    int end = min(base + CHUNK, e);
    for (int i = base + t; i < end; i += 256) {
        int sv = src[i], dv = dst[i];
        int pos = atomicAdd(&cur[dv >> 8], 1);
        ebuf[pos] = sv | ((dv & 255) << 24);
    }
}

__global__ __launch_bounds__(256) void k_build(const int* __restrict__ ebuf,
                                               const int* __restrict__ boff,
                                               int* __restrict__ off,
                                               int* __restrict__ csr) {
    __shared__ int ec[ECAP];
    __shared__ int h[256];
    __shared__ int cur[256];
    int t = threadIdx.x, b = blockIdx.x;
    int node0 = b << 8;
    int e0 = boff[b], e1 = boff[b + 1];
    int ne = e1 - e0;
    bool fits = (ne <= ECAP);
    h[t] = 0;
    __syncthreads();
    if (fits) {
        for (int i = t; i < ne; i += 256) {
            int p = ebuf[e0 + i];
            ec[i] = p;
            atomicAdd(&h[(unsigned)p >> 24], 1);
        }
    } else {
        for (int i = t; i < ne; i += 256)
            atomicAdd(&h[(unsigned)ebuf[e0 + i] >> 24], 1);
    }
    __syncthreads();
    int mydeg = h[t];
    #pragma unroll
    for (int d = 1; d < 256; d <<= 1) {
        int tv = (t >= d) ? h[t - d] : 0;
        __syncthreads();
        h[t] += tv;
        __syncthreads();
    }
    int node = node0 + t;
    if (node < N_NODES) off[node + 1] = e0 + h[t];
    if (b == 0 && t == 0) off[0] = 0;
    cur[t] = e0 + h[t] - mydeg;
    __syncthreads();
    if (fits) {
        for (int i = t; i < ne; i += 256) {
            int p = ec[i];
            int pos = atomicAdd(&cur[(unsigned)p >> 24], 1);
            csr[pos] = p & 0xFFFFFF;
        }
    } else {
        for (int i = t; i < ne; i += 256) {
            int p = ebuf[e0 + i];
            int pos = atomicAdd(&cur[(unsigned)p >> 24], 1);
            csr[pos] = p & 0xFFFFFF;
        }
    }
}

// ---------------- layer-1 aggregation (i8 gather) ----------------
// Gather loop untouched (frozen, miss-path floor). Epilogue writes rst in
// A-fragment-staging order.

__global__ void k_agg_i8(const signed char* __restrict__ h8, const float* __restrict__ hs,
                         const int* __restrict__ off, const int* __restrict__ csr,
                         const float* __restrict__ eps_p,
                         bf16_t* __restrict__ rst, int n) {
    int gid = blockIdx.x * blockDim.x + threadIdx.x;
    int u = __builtin_amdgcn_readfirstlane(gid >> 6);   // wave-uniform
    int lane = threadIdx.x & 63;
    if (u >= n) return;

    float acc0 = 0.f, acc1 = 0.f;
    int r0 = off[u], r1 = off[u + 1];
    unsigned loff = lane * 2u;

    for (int base = r0; base < r1; base += 64) {
        int m = r1 - base; if (m > 64) m = 64;           // uniform
        int li = (lane < m) ? lane : (m - 1);
        int iv = csr[base + li];                         // one coalesced load
        for (int c = 0; c < m; c += 16) {
            int s[16]; float sc[16]; unsigned v[16];
            #pragma unroll
            for (int t = 0; t < 16; t++)
                s[t] = __builtin_amdgcn_readlane(iv, c + t);   // SGPR indices
            #pragma unroll
            for (int t = 0; t < 16; t++)
                sc[t] = (c + t < m) ? hs[s[t]] : 0.f;          // scalar loads
            #pragma unroll
            for (int t = 0; t < 16; t++)
                v[t] = *(const unsigned short*)(h8 + (((unsigned)s[t] << 7) + loff));
            #pragma unroll
            for (int t = 0; t < 16; t++) {
                acc0 += (float)(int)(signed char)(v[t] & 0xffu) * sc[t];
                acc1 += (float)(int)(signed char)(v[t] >> 8) * sc[t];
            }
        }
    }

    float scu = hs[u] * (1.0f + eps_p[0]);
    unsigned vu = *(const unsigned short*)(h8 + (((unsigned)u << 7) + loff));
    float o0 = (float)(int)(signed char)(vu & 0xffu) * scu + acc0;
    float o1 = (float)(int)(signed char)(vu >> 8) * scu + acc1;

    int R = u >> 6, rr = u & 63;
    int i4 = rr >> 4, l15v = rr & 15;
    int ks = lane >> 4, quad = (lane >> 2) & 3, e2 = (lane & 3) * 2;
    size_t pos = (((size_t)R * 4 + ks) * 256 + (size_t)(i4 * 64 + quad * 16 + l15v)) * 8 + e2;
    *(unsigned int*)(rst + pos) =
        (unsigned int)f2b(o0) | ((unsigned int)f2b(o1) << 16);
}

// ---------------- layer-2 aggregation (u8 gather) ----------------

__global__ void k_agg_u8(const unsigned char* __restrict__ h8,
                         const float* __restrict__ hs,
                         const int* __restrict__ off, const int* __restrict__ csr,
                         const float* __restrict__ eps_p,
                         bf16_t* __restrict__ rst, int n) {
    int gid = blockIdx.x * blockDim.x + threadIdx.x;
    int u = __builtin_amdgcn_readfirstlane(gid >> 6);   // wave-uniform
    int lane = threadIdx.x & 63;
    if (u >= n) return;

    float acc[4] = {0.f, 0.f, 0.f, 0.f};
    int r0 = off[u], r1 = off[u + 1];
    unsigned loff = lane * 4u;

    for (int base = r0; base < r1; base += 64) {
        int m = r1 - base; if (m > 64) m = 64;           // uniform
        int li = (lane < m) ? lane : (m - 1);
        int iv = csr[base + li];                         // one coalesced load
        for (int c = 0; c < m; c += 16) {
            int s[16]; float sc[16]; unsigned int v[16];
            #pragma unroll
            for (int t = 0; t < 16; t++)
                s[t] = __builtin_amdgcn_readlane(iv, c + t);   // SGPR indices
            #pragma unroll
            for (int t = 0; t < 16; t++)
                sc[t] = (c + t < m) ? hs[s[t]] : 0.f;          // scalar loads
            #pragma unroll
            for (int t = 0; t < 16; t++)
                v[t] = *(const unsigned int*)(h8 + (((unsigned)s[t] << 8) + loff));
            #pragma unroll
            for (int t = 0; t < 16; t++) {
                acc[0] += (float)(v[t] & 0xffu) * sc[t];
                acc[1] += (float)((v[t] >> 8) & 0xffu) * sc[t];
                acc[2] += (float)((v[t] >> 16) & 0xffu) * sc[t];
                acc[3] += (float)(v[t] >> 24) * sc[t];
            }
        }
    }

    float ep = 1.0f + eps_p[0];
    unsigned int vu = *(const unsigned int*)(h8 + (((unsigned)u << 8) + loff));
    float scu = hs[u] * ep;
    float o0 = (float)(vu & 0xffu) * scu + acc[0];
    float o1 = (float)((vu >> 8) & 0xffu) * scu + acc[1];
    float o2 = (float)((vu >> 16) & 0xffu) * scu + acc[2];
    float o3 = (float)(vu >> 24) * scu + acc[3];
    uint2 ov;
    ov.x = (unsigned int)f2b(o0) | ((unsigned int)f2b(o1) << 16);
    ov.y = (unsigned int)f2b(o2) | ((unsigned int)f2b(o3) << 16);

    int R = u >> 6, rr = u & 63;
    int i4 = rr >> 4, l15v = rr & 15;
    int ks = lane >> 3, quad = (lane >> 1) & 3, e4 = (lane & 1) * 4;
    size_t pos = (((size_t)R * 8 + ks) * 256 + (size_t)(i4 * 64 + quad * 16 + l15v)) * 8 + e4;
    *(uint2*)(rst + pos) = ov;
}

// ---------------- fused 2-GEMM MLP: A staged once, B global-direct ----------
// R11 analysis: resident A-tiles (1024 x 32KB = 32MB) saturate aggregate L2,
// and each tile is read 4x (once per wave) -> re-reads thrash to L3. Fix:
// stage the A-tile into LDS ONCE per block (linear gl_lds16 burst; rst is
// already in staging order), alias the buffer with Ts (A dead when Ts born).
// Phase-1 af reads become conflict-free lane-linear LDS reads. B (weights,
// L2-permanently-hot, read once per block) stays global-direct. Only 2-4
// barriers per block total. LDS = 32KB union -> 4 blocks/CU.
// Strides: A [block][NS1][2048 elems]; W [kstep][1024 chunks][8] ->
// (k*1024+chunk)*8; FCt -> (k*256+chunk)*8.
// OUT8: u8 + per-row scale. FUSE_FC: phase 3 = h @ fc + bias -> fp32 out.

template <int K1, bool OUT8, bool FUSE_FC>
__global__ __launch_bounds__(256, 4) void k_mlp(
    const bf16_t* __restrict__ A, const bf16_t* __restrict__ W1t,
    const bf16_t* __restrict__ W2t, bf16_t* __restrict__ H,
    unsigned char* __restrict__ H8, float* __restrict__ Hs,
    const bf16_t* __restrict__ FCt, const float* __restrict__ fc_b,
    float* __restrict__ Cout, int M)
{
    constexpr int NS1 = K1 / 32;
    __shared__ __align__(16) bf16_t UU[64 * 256];   // 32 KB union: As (ph1) / Ts (ph2+)
    __shared__ int rmax[64];

    int tid = threadIdx.x;
    int wave = tid >> 6, lane = tid & 63;
    int l15 = lane & 15, quad = lane >> 4;
    int bm = blockIdx.x * 64;
    int wn = wave * 64;   // wave owns 64 cols (4 col-tiles)

    // staged Ts element index for (row, col) in [64]x[256]
    auto ts_el = [&](int row, int col) {
        return ((col >> 5) * 4 + (row >> 4)) * 512 +
               ((((col >> 3) & 3) * 16) + (row & 15)) * 8 + (col & 7);
    };

    // ---- prologue: stage A-tile (NS1*2048 elems) linearly into UU ----
    const bf16_t* Ab = A + (size_t)blockIdx.x * NS1 * 2048;
    #pragma unroll
    for (int rr = 0; rr < NS1; rr++)
        gl_lds16(Ab + (size_t)rr * 2048 + tid * 8, &UU[rr * 2048 + tid * 8]);

    f32x4 acc[4][4];
    #pragma unroll
    for (int i = 0; i < 4; i++)
        #pragma unroll
        for (int j = 0; j < 4; j++) acc[i][j] = 0.f;

    __syncthreads();   // A-tile resident

    // ---- phase 1: A (LDS, staged) x W1t (global-direct, L2-hot) ----
    #pragma unroll
    for (int k = 0; k < NS1; k++) {
        short8 af[4], bfv[4];
        #pragma unroll
        for (int i = 0; i < 4; i++)
            af[i] = *(const short8*)&UU[k * 2048 + (i * 64 + lane) * 8];
        #pragma unroll
        for (int j = 0; j < 4; j++)
            bfv[j] = *(const short8*)(W1t + ((size_t)k * 1024 + (wave * 4 + j) * 64 + lane) * 8);
        #pragma unroll
        for (int i = 0; i < 4; i++)
            #pragma unroll
            for (int j = 0; j < 4; j++)
                acc[i][j] = __builtin_amdgcn_mfma_f32_16x16x32_bf16(af[i], bfv[j], acc[i][j], 0, 0, 0);
    }

    __syncthreads();   // all As reads done before Ts overwrite

    // write relu(h1) into staged Ts (reuses UU)
    #pragma unroll
    for (int i = 0; i < 4; i++)
        #pragma unroll
        for (int j = 0; j < 4; j++) {
            int col = wn + j * 16 + l15;
            #pragma unroll
            for (int r = 0; r < 4; r++) {
                int row = i * 16 + quad * 4 + r;
                UU[ts_el(row, col)] = f2b(fmaxf(acc[i][j][r], 0.f));
            }
        }

    #pragma unroll
    for (int i = 0; i < 4; i++)
        #pragma unroll
        for (int j = 0; j < 4; j++) acc[i][j] = 0.f;
    __syncthreads();

    // ---- phase 2: relu(T) (LDS, staged) x W2t (global-direct) ----
    #pragma unroll
    for (int k = 0; k < 8; k++) {
        short8 af[4], bfv[4];
        #pragma unroll
        for (int i = 0; i < 4; i++)
            af[i] = *(const short8*)&UU[((k * 4 + i) * 64 + lane) * 8];
        #pragma unroll
        for (int j = 0; j < 4; j++)
            bfv[j] = *(const short8*)(W2t + ((size_t)k * 1024 + (wave * 4 + j) * 64 + lane) * 8);
        #pragma unroll
        for (int i = 0; i < 4; i++)
            #pragma unroll
            for (int j = 0; j < 4; j++)
                acc[i][j] = __builtin_amdgcn_mfma_f32_16x16x32_bf16(af[i], bfv[j], acc[i][j], 0, 0, 0);
    }

    if constexpr (OUT8) {
        if (tid < 64) rmax[tid] = 0;
        __syncthreads();
        #pragma unroll
        for (int i = 0; i < 4; i++)
            #pragma unroll
            for (int r = 0; r < 4; r++) {
                float m = 0.f;
                #pragma unroll
                for (int j = 0; j < 4; j++) m = fmaxf(m, acc[i][j][r]);
                atomicMax(&rmax[i * 16 + quad * 4 + r], __float_as_int(m));
            }
        __syncthreads();
        #pragma unroll
        for (int i = 0; i < 4; i++) {
            #pragma unroll
            for (int r = 0; r < 4; r++) {
                int row = i * 16 + quad * 4 + r;
                int rowg = bm + row;
                if (rowg >= M) continue;
                float rm = __int_as_float(rmax[row]);
                float inv = (rm > 0.f) ? 255.f / rm : 0.f;
                #pragma unroll
                for (int j = 0; j < 4; j++) {
                    int col = wn + j * 16 + l15;
                    float v = fmaxf(acc[i][j][r], 0.f);
                    unsigned q = (unsigned)(v * inv + 0.5f);
                    if (q > 255u) q = 255u;
                    H8[(size_t)rowg * 256 + col] = (unsigned char)q;
                }
                if (wave == 0 && l15 == 0)
                    Hs[rowg] = rm * (1.f / 255.f);
            }
        }
    } else if constexpr (FUSE_FC) {
        // protect phase-2's Ts readers, then overwrite Ts with relu(h2)
        __syncthreads();
        #pragma unroll
        for (int i = 0; i < 4; i++)
            #pragma unroll
            for (int j = 0; j < 4; j++) {
                int col = wn + j * 16 + l15;
                #pragma unroll
                for (int r = 0; r < 4; r++) {
                    int row = i * 16 + quad * 4 + r;
                    UU[ts_el(row, col)] = f2b(fmaxf(acc[i][j][r], 0.f));
                }
            }
        __syncthreads();

        // phase 3: each wave computes rows [wave*16, wave*16+16), cols 0..47
        f32x4 acc3[3];
        #pragma unroll
        for (int j = 0; j < 3; j++) acc3[j] = 0.f;

        #pragma unroll
        for (int k = 0; k < 8; k++) {
            short8 af = *(const short8*)&UU[((k * 4 + wave) * 64 + lane) * 8];
            #pragma unroll
            for (int j = 0; j < 3; j++) {
                short8 bfv = *(const short8*)(FCt + ((size_t)k * 256 + j * 64 + lane) * 8);
                acc3[j] = __builtin_amdgcn_mfma_f32_16x16x32_bf16(af, bfv, acc3[j], 0, 0, 0);
            }
        }

        #pragma unroll
        for (int j = 0; j < 3; j++) {
            int col = j * 16 + l15;
            if (col >= DIM_C) continue;
            float bv = fc_b[col];
            #pragma unroll
            for (int r = 0; r < 4; r++) {
                int rowg = bm + wave * 16 + quad * 4 + r;
                if (rowg < M)
                    Cout[(size_t)rowg * DIM_C + col] = acc3[j][r] + bv;
            }
        }
    } else {
        #pragma unroll
        for (int j = 0; j < 4; j++) {
            int col = wn + j * 16 + l15;
            #pragma unroll
            for (int i = 0; i < 4; i++) {
                #pragma unroll
                for (int r = 0; r < 4; r++) {
                    int rowg = bm + i * 16 + quad * 4 + r;
                    if (rowg < M)
                        H[(size_t)rowg * 256 + col] = f2b(fmaxf(acc[i][j][r], 0.f));
                }
            }
        }
    }
}

// ---------------- launch ----------------

static inline size_t rnd256(size_t x) { return (x + 255) & ~(size_t)255; }

extern "C" void kernel_launch(void* const* d_in, const int* in_sizes, int n_in,
                              void* d_out, int out_size, void* d_ws, size_t ws_size,
                              hipStream_t stream) {
    const float* x    = (const float*)d_in[0];
    const int*   src  = (const int*)d_in[1];
    const int*   dst  = (const int*)d_in[2];
    const float* eps1 = (const float*)d_in[3];
    const float* w1a  = (const float*)d_in[4];
    const float* w1b  = (const float*)d_in[5];
    const float* eps2 = (const float*)d_in[6];
    const float* w2a  = (const float*)d_in[7];
    const float* w2b  = (const float*)d_in[8];
    const float* fc_w = (const float*)d_in[9];
    const float* fc_b = (const float*)d_in[10];
    float* out = (float*)d_out;

    char* w = (char*)d_ws;
    int* off  = (int*)w; w += rnd256(sizeof(int) * (size_t)(N_NODES + 1));
    int* csr  = (int*)w; w += rnd256(sizeof(int) * (size_t)N_EDGES);
    int* cnt2  = (int*)w; w += rnd256(sizeof(int) * (size_t)NBLK * NB);
    int* basep = (int*)w; w += rnd256(sizeof(int) * (size_t)NBLK * NB);
    int* btot  = (int*)w; w += rnd256(sizeof(int) * 512);
    int* boff  = (int*)w; w += rnd256(sizeof(int) * (NB + 1));
    bf16_t* w1a_t = (bf16_t*)w; w += rnd256(2 * (size_t)DIM_H * DIM_IN);
    bf16_t* w1b_t = (bf16_t*)w; w += rnd256(2 * (size_t)DIM_H * DIM_H);
    bf16_t* w2a_t = (bf16_t*)w; w += rnd256(2 * (size_t)DIM_H * DIM_H);
    bf16_t* w2b_t = (bf16_t*)w; w += rnd256(2 * (size_t)DIM_H * DIM_H);
    bf16_t* fc_t  = (bf16_t*)w; w += rnd256(2 * (size_t)128 * DIM_H);
    signed char* x8 = (signed char*)w; w += rnd256((size_t)N_NODES * DIM_IN);
    float* xs = (float*)w; w += rnd256(sizeof(float) * (size_t)N_NODES);
    unsigned char* h8 = (unsigned char*)w; w += rnd256((size_t)N_NODES * DIM_H);
    float* hs = (float*)w; w += rnd256(sizeof(float) * (size_t)N_NODES);
    bf16_t* R12 = (bf16_t*)w; w += rnd256(2 * (size_t)NPAD * DIM_H);
    bf16_t* R3  = (bf16_t*)w; w += rnd256(2 * (size_t)NPAD * DIM_H);

    bf16_t* rst1 = R12;       // [1563][4][256][8] staging order, 25.6 MB
    int* ebuf = (int*)R3;     // 6.4 MB, dead before layer-2 agg writes R3
    int* ticket = btot + 500; // btot block has 512 ints, NB=391 used

    // ---- prep (hist + cvt + wcvt fused) ----
    k_prep<<<NBLK + CVT_BLOCKS + WCVT_BLOCKS, 256, 0, stream>>>(
        dst, cnt2, x, x8, xs, w1a, w1b, w2a, w2b, fc_w,
        w1a_t, w1b_t, w2a_t, w2b_t, fc_t, ticket);

    // ---- CSR build (scanA + scan2 fused via ticket) ----
    k_bscanA<<<NB, 512, 0, stream>>>(cnt2, basep, btot, ticket, boff);
    k_bscatter<<<NBLK, 256, 0, stream>>>(src, dst, basep, boff, ebuf, N_EDGES);
    k_build<<<NB, 256, 0, stream>>>(ebuf, boff, off, csr);

    const int agg_blocks = (N_NODES * 64 + 255) / 256;
    const int mlp_blocks = NPAD / 64;   // 1563

    // ---- layer 1: i8 agg -> MLP (u8 output + row scales) ----
    k_agg_i8<<<agg_blocks, 256, 0, stream>>>(x8, xs, off, csr, eps1, rst1, N_NODES);
    k_mlp<DIM_IN, true, false><<<mlp_blocks, 256, 0, stream>>>(
        rst1, w1a_t, w1b_t, nullptr, h8, hs, nullptr, nullptr, nullptr, N_NODES);

    // ---- layer 2: u8 agg -> MLP + fused fc (fp32 out) ----
    k_agg_u8<<<agg_blocks, 256, 0, stream>>>(h8, hs, off, csr, eps2, (bf16_t*)R3, N_NODES);
    k_mlp<DIM_H, false, true><<<mlp_blocks, 256, 0, stream>>>(
        (bf16_t*)R3, w2a_t, w2b_t, nullptr, nullptr, nullptr, fc_t, fc_b, out, N_NODES);
}